// Round 4
// baseline (1514.714 us; speedup 1.0000x reference)
//
#include <hip/hip_runtime.h>

#define N_NODES 150000
#define N_EDGES 2400000
#define D 32
#define NB 128  // destination nodes per block in fused layer kernels
#define SCAN_BLK 256
#define NBLK_SCAN ((N_NODES + SCAN_BLK - 1) / SCAN_BLK)  // 586

// ---------- CSR build ----------
__global__ void k_zero_int(int* __restrict__ p, int n) {
    int i = blockIdx.x * blockDim.x + threadIdx.x;
    if (i < n) p[i] = 0;
}

// count degrees AND record each edge's within-destination slot
__global__ void k_count_pos(const int* __restrict__ dst, int* __restrict__ deg,
                            int* __restrict__ pos) {
    int e = blockIdx.x * blockDim.x + threadIdx.x;
    if (e < N_EDGES) pos[e] = atomicAdd(&deg[dst[e]], 1);
}

__global__ void k_scan1(const int* __restrict__ deg, int* __restrict__ row,
                        int* __restrict__ part) {
    __shared__ int s[SCAN_BLK];
    int t = threadIdx.x, i = blockIdx.x * SCAN_BLK + t;
    int v = (i < N_NODES) ? deg[i] : 0;
    s[t] = v;
    __syncthreads();
    for (int off = 1; off < SCAN_BLK; off <<= 1) {
        int add = (t >= off) ? s[t - off] : 0;
        __syncthreads();
        s[t] += add;
        __syncthreads();
    }
    if (i < N_NODES) row[i] = s[t] - v;  // exclusive within block
    if (t == SCAN_BLK - 1) part[blockIdx.x] = s[t];
}

__global__ void k_scan2(int* __restrict__ part) {
    __shared__ int s[1024];
    int t = threadIdx.x;
    int v = (t < NBLK_SCAN) ? part[t] : 0;
    s[t] = v;
    __syncthreads();
    for (int off = 1; off < 1024; off <<= 1) {
        int add = (t >= off) ? s[t - off] : 0;
        __syncthreads();
        s[t] += add;
        __syncthreads();
    }
    if (t < NBLK_SCAN) part[t] = s[t] - v;  // exclusive block offsets
}

__global__ void k_scan3(const int* __restrict__ deg, int* __restrict__ row,
                        const int* __restrict__ part, float* __restrict__ dis) {
    int i = blockIdx.x * blockDim.x + threadIdx.x;
    if (i < N_NODES) {
        row[i] += part[i >> 8];
        dis[i] = rsqrtf((float)deg[i] + 1.0f);  // +1 self-loop
    }
    if (i == 0) row[N_NODES] = N_EDGES;
}

// non-atomic fill: csr2[slot] = (src, dst)
__global__ void k_fill2(const int* __restrict__ src, const int* __restrict__ dst,
                        const int* __restrict__ pos, const int* __restrict__ row,
                        int2* __restrict__ csr2) {
    int e = blockIdx.x * blockDim.x + threadIdx.x;
    if (e >= N_EDGES) return;
    int d = dst[e];
    csr2[row[d] + pos[e]] = make_int2(src[e], d);
}

// ---------- fc1: hsc0 = relu(x @ fc1_w + b) * dis ----------
__global__ void k_fc1(const float* __restrict__ x, const float* __restrict__ w,
                      const float* __restrict__ b, const float* __restrict__ dis,
                      float* __restrict__ hsc) {
    int t = blockIdx.x * blockDim.x + threadIdx.x;
    if (t >= N_NODES * D) return;
    int i = t >> 5, f = t & 31;
    float v = fmaf(x[2 * i], w[f], fmaf(x[2 * i + 1], w[D + f], b[f]));
    v = v > 0.f ? v : 0.f;
    hsc[t] = v * dis[i];
}

// ---------- fused layer: edge-parallel LDS-atomic gather + transform ----------
// hout = relu( (dis_i * Σ_{s∈N(i)∪{i}} hsc[s]) @ W + b ) * dis_i
__global__ __launch_bounds__(256) void k_layer(const float* __restrict__ hsc,
                                               const int* __restrict__ row,
                                               const int2* __restrict__ csr2,
                                               const float* __restrict__ dis,
                                               const float* __restrict__ W,
                                               const float* __restrict__ b,
                                               float* __restrict__ hout) {
    __shared__ float acc[NB * 33];
    int t = threadIdx.x;
    int n0 = blockIdx.x * NB;
    int n1 = n0 + NB;
    if (n1 > N_NODES) n1 = N_NODES;
    int nb = n1 - n0;
    int f = t & 31;

    float wcol[D];  // column f of W, per lane
#pragma unroll
    for (int k = 0; k < D; ++k) wcol[k] = W[k * D + f];

    // init acc with self-loop term
    for (int idx = t; idx < nb * D; idx += 256) {
        int i = idx >> 5, ff = idx & 31;
        acc[i * 33 + ff] = hsc[(n0 + i) * D + ff];
    }
    __syncthreads();

    // edge-parallel gather: 32 edges in flight, 8 lanes (float4) each
    int rs = row[n0], re = row[n1];
    int g = t >> 3, l = t & 7;
    for (int e = rs + g; e < re; e += 32) {
        int2 sd = csr2[e];
        float4 v = ((const float4*)hsc)[sd.x * 8 + l];
        int base = (sd.y - n0) * 33 + l * 4;
        atomicAdd(&acc[base + 0], v.x);
        atomicAdd(&acc[base + 1], v.y);
        atomicAdd(&acc[base + 2], v.z);
        atomicAdd(&acc[base + 3], v.w);
    }
    __syncthreads();

    // transform: 8 node-groups of 32 lanes; LDS broadcast reads vs VGPR wcol
    int g5 = t >> 5;
    for (int n = g5; n < nb; n += 8) {
        float s = 0.f;
#pragma unroll
        for (int k = 0; k < D; ++k) s = fmaf(acc[n * 33 + k], wcol[k], s);
        float di = dis[n0 + n];
        float v = fmaf(s, di, b[f]);
        v = v > 0.f ? v : 0.f;
        hout[(n0 + n) * D + f] = v * di;
    }
}

// ---------- heads: shared gather, two transforms + relu + 32->1 dots ----------
__global__ __launch_bounds__(256) void k_heads(
    const float* __restrict__ hsc, const int* __restrict__ row,
    const int2* __restrict__ csr2, const float* __restrict__ dis,
    const float* __restrict__ W1, const float* __restrict__ b1,
    const float* __restrict__ W2, const float* __restrict__ b2,
    const float* __restrict__ fw1, const float* __restrict__ fb1,
    const float* __restrict__ fw2, const float* __restrict__ fb2,
    float* __restrict__ out) {
    __shared__ float acc[NB * 33];
    int t = threadIdx.x;
    int n0 = blockIdx.x * NB;
    int n1 = n0 + NB;
    if (n1 > N_NODES) n1 = N_NODES;
    int nb = n1 - n0;
    int f = t & 31;

    float w1[D], w2[D];
#pragma unroll
    for (int k = 0; k < D; ++k) { w1[k] = W1[k * D + f]; w2[k] = W2[k * D + f]; }

    for (int idx = t; idx < nb * D; idx += 256) {
        int i = idx >> 5, ff = idx & 31;
        acc[i * 33 + ff] = hsc[(n0 + i) * D + ff];
    }
    __syncthreads();

    int rs = row[n0], re = row[n1];
    int g = t >> 3, l = t & 7;
    for (int e = rs + g; e < re; e += 32) {
        int2 sd = csr2[e];
        float4 v = ((const float4*)hsc)[sd.x * 8 + l];
        int base = (sd.y - n0) * 33 + l * 4;
        atomicAdd(&acc[base + 0], v.x);
        atomicAdd(&acc[base + 1], v.y);
        atomicAdd(&acc[base + 2], v.z);
        atomicAdd(&acc[base + 3], v.w);
    }
    __syncthreads();

    int g5 = t >> 5;
    for (int n = g5; n < nb; n += 8) {
        float s1 = 0.f, s2 = 0.f;
#pragma unroll
        for (int k = 0; k < D; ++k) {
            float ak = acc[n * 33 + k];
            s1 = fmaf(ak, w1[k], s1);
            s2 = fmaf(ak, w2[k], s2);
        }
        float di = dis[n0 + n];
        float v1 = fmaf(s1, di, b1[f]);
        v1 = (v1 > 0.f ? v1 : 0.f) * fw1[f];
        float v2 = fmaf(s2, di, b2[f]);
        v2 = (v2 > 0.f ? v2 : 0.f) * fw2[f];
#pragma unroll
        for (int o = 16; o > 0; o >>= 1) {
            v1 += __shfl_down(v1, o, 32);
            v2 += __shfl_down(v2, o, 32);
        }
        if (f == 0) {
            int i = n0 + n;
            out[i * 2] = v1 + fb1[0];
            out[i * 2 + 1] = v2 + fb2[0];
        }
    }
}

extern "C" void kernel_launch(void* const* d_in, const int* in_sizes, int n_in,
                              void* d_out, int out_size, void* d_ws, size_t ws_size,
                              hipStream_t stream) {
    const float* x       = (const float*)d_in[0];
    const int*   eidx    = (const int*)d_in[1];
    const float* fc1_w   = (const float*)d_in[2];
    const float* fc1_b   = (const float*)d_in[3];
    const float* conv1_w = (const float*)d_in[4];
    const float* conv1_b = (const float*)d_in[5];
    const float* conv2_w = (const float*)d_in[6];
    const float* conv2_b = (const float*)d_in[7];
    const float* c31_w   = (const float*)d_in[8];
    const float* c31_b   = (const float*)d_in[9];
    const float* c32_w   = (const float*)d_in[10];
    const float* c32_b   = (const float*)d_in[11];
    const float* fc21_w  = (const float*)d_in[12];
    const float* fc21_b  = (const float*)d_in[13];
    const float* fc22_w  = (const float*)d_in[14];
    const float* fc22_b  = (const float*)d_in[15];
    float* out = (float*)d_out;

    const int* src = eidx;            // edge_index[0]
    const int* dst = eidx + N_EDGES;  // edge_index[1]

    // workspace layout (int/float units; offsets keep 16B alignment for HA/HB)
    int*   wsb   = (int*)d_ws;
    int2*  csr2  = (int2*)wsb;                         // 2.4M int2 = 4.8M ints, offset 0 (8B aligned)
    int*   irow  = wsb + 4800000;                      // N+1 (padded to 150004)
    int*   ipart = wsb + 4950004;                      // 1024
    int*   ideg  = wsb + 4951028;                      // N
    float* dis   = (float*)(wsb + 5101028);            // N
    float* HA    = (float*)(wsb + 5251028);            // N*D, 16B aligned
    float* HB    = (float*)(wsb + 10051028);           // N*D, 16B aligned
    int*   ipos  = (int*)HA;                           // E, aliases HA (dead before fc1)

    const int BLK = 256;
    const int gN  = (N_NODES + BLK - 1) / BLK;
    const int gND = (N_NODES * D + BLK - 1) / BLK;
    const int gE  = (N_EDGES + BLK - 1) / BLK;
    const int gL  = (N_NODES + NB - 1) / NB;  // 1172 blocks for layer kernels

    // ----- CSR build + normalization -----
    k_zero_int<<<gN, BLK, 0, stream>>>(ideg, N_NODES);
    k_count_pos<<<gE, BLK, 0, stream>>>(dst, ideg, ipos);
    k_scan1<<<NBLK_SCAN, SCAN_BLK, 0, stream>>>(ideg, irow, ipart);
    k_scan2<<<1, 1024, 0, stream>>>(ipart);
    k_scan3<<<gN, BLK, 0, stream>>>(ideg, irow, ipart, dis);
    k_fill2<<<gE, BLK, 0, stream>>>(src, dst, ipos, irow, csr2);

    // ----- network -----
    k_fc1<<<gND, BLK, 0, stream>>>(x, fc1_w, fc1_b, dis, HA);
    k_layer<<<gL, BLK, 0, stream>>>(HA, irow, csr2, dis, conv1_w, conv1_b, HB);
    k_layer<<<gL, BLK, 0, stream>>>(HB, irow, csr2, dis, conv2_w, conv2_b, HA);
    k_heads<<<gL, BLK, 0, stream>>>(HA, irow, csr2, dis, c31_w, c31_b, c32_w, c32_b,
                                    fc21_w, fc21_b, fc22_w, fc22_b, out);
}

// Round 5
// 450.360 us; speedup vs baseline: 3.3633x; 3.3633x over previous
//
#include <hip/hip_runtime.h>

#define N_NODES 150000
#define N_EDGES 2400000
#define D 32
#define SCAN_BLK 256
#define NBLK_SCAN ((N_NODES + SCAN_BLK - 1) / SCAN_BLK)  // 586
#define CSR_CAP (N_EDGES + 15 * N_NODES)                 // 4,650,000 (exact worst case)

// ---------- CSR build ----------
__global__ void k_zero_int(int* __restrict__ p, int n) {
    int i = blockIdx.x * blockDim.x + threadIdx.x;
    if (i < n) p[i] = 0;
}

__global__ void k_fill_const(int* __restrict__ p, int n, int v) {
    int i = blockIdx.x * blockDim.x + threadIdx.x;
    if (i < n) p[i] = v;
}

__global__ void k_zero_row(float* __restrict__ HA, float* __restrict__ HB) {
    int t = threadIdx.x;  // 32 threads
    HA[N_NODES * D + t] = 0.f;
    HB[N_NODES * D + t] = 0.f;
}

// count degrees AND record each edge's within-destination slot
__global__ void k_count_pos(const int* __restrict__ dst, int* __restrict__ deg,
                            int* __restrict__ pos) {
    int e = blockIdx.x * blockDim.x + threadIdx.x;
    if (e < N_EDGES) pos[e] = atomicAdd(&deg[dst[e]], 1);
}

// scan PADDED degrees (round up to 16)
__global__ void k_scan1(const int* __restrict__ deg, int* __restrict__ row,
                        int* __restrict__ part) {
    __shared__ int s[SCAN_BLK];
    int t = threadIdx.x, i = blockIdx.x * SCAN_BLK + t;
    int v = (i < N_NODES) ? ((deg[i] + 15) & ~15) : 0;
    s[t] = v;
    __syncthreads();
    for (int off = 1; off < SCAN_BLK; off <<= 1) {
        int add = (t >= off) ? s[t - off] : 0;
        __syncthreads();
        s[t] += add;
        __syncthreads();
    }
    if (i < N_NODES) row[i] = s[t] - v;  // exclusive within block
    if (t == SCAN_BLK - 1) part[blockIdx.x] = s[t];
}

__global__ void k_scan2(int* __restrict__ part, int* __restrict__ row) {
    __shared__ int s[1024];
    int t = threadIdx.x;
    int v = (t < NBLK_SCAN) ? part[t] : 0;
    s[t] = v;
    __syncthreads();
    for (int off = 1; off < 1024; off <<= 1) {
        int add = (t >= off) ? s[t - off] : 0;
        __syncthreads();
        s[t] += add;
        __syncthreads();
    }
    if (t < NBLK_SCAN) part[t] = s[t] - v;     // exclusive block offsets
    if (t == NBLK_SCAN - 1) row[N_NODES] = s[t];  // padded grand total
}

__global__ void k_scan3(const int* __restrict__ deg, int* __restrict__ row,
                        const int* __restrict__ part, float* __restrict__ dis) {
    int i = blockIdx.x * blockDim.x + threadIdx.x;
    if (i < N_NODES) {
        row[i] += part[i >> 8];
        dis[i] = rsqrtf((float)deg[i] + 1.0f);  // +1 self-loop
    }
}

// non-atomic fill using saved positions (pad slots keep N_NODES from k_fill_const)
__global__ void k_fill(const int* __restrict__ src, const int* __restrict__ dst,
                       const int* __restrict__ pos, const int* __restrict__ row,
                       int* __restrict__ csr) {
    int e = blockIdx.x * blockDim.x + threadIdx.x;
    if (e >= N_EDGES) return;
    csr[row[dst[e]] + pos[e]] = src[e];
}

// ---------- fc1: hsc0 = relu(x @ fc1_w + b) * dis ----------
__global__ void k_fc1(const float* __restrict__ x, const float* __restrict__ w,
                      const float* __restrict__ b, const float* __restrict__ dis,
                      float* __restrict__ hsc) {
    int t = blockIdx.x * blockDim.x + threadIdx.x;
    if (t >= N_NODES * D) return;
    int i = t >> 5, f = t & 31;
    float v = fmaf(x[2 * i], w[f], fmaf(x[2 * i + 1], w[D + f], b[f]));
    v = v > 0.f ? v : 0.f;
    hsc[t] = v * dis[i];
}

// ---------- fused layer: hout = relu( (dis_i * Σ_{s∈N(i)∪{i}} hsc[s]) @ W + b ) * dis_i ----------
__global__ __launch_bounds__(256) void k_layer(const float* __restrict__ hsc,
                                               const int* __restrict__ row,
                                               const int* __restrict__ csr,
                                               const float* __restrict__ dis,
                                               const float* __restrict__ W,
                                               const float* __restrict__ b,
                                               float* __restrict__ hout) {
    __shared__ float Ws[D * D];
    for (int k = threadIdx.x; k < D * D; k += 256) Ws[k] = W[k];
    __syncthreads();
    int t = blockIdx.x * 256 + threadIdx.x;
    int i = t >> 5, f = t & 31;
    if (i >= N_NODES) return;
    float a = hsc[t];  // self-loop
    int rs = row[i], re = row[i + 1];
    for (int j0 = rs; j0 < re; j0 += 16) {  // row length is a multiple of 16
        int sidx = csr[j0 + (f & 15)];
        float v[16];
#pragma unroll
        for (int j = 0; j < 16; ++j) {
            int s = __shfl(sidx, j, 32);
            v[j] = hsc[s * D + f];  // 16 independent loads in flight
        }
#pragma unroll
        for (int j = 0; j < 16; ++j) a += v[j];
    }
    float di = dis[i];
    a *= di;  // aggregated feature f of node i
    float acc = 0.f;
#pragma unroll
    for (int k = 0; k < D; ++k) {
        float ak = __shfl(a, k, 32);
        acc = fmaf(ak, Ws[k * D + f], acc);
    }
    float v = acc + b[f];
    v = v > 0.f ? v : 0.f;
    hout[t] = v * di;
}

// ---------- heads: one gather, two transforms + relu + 32->1 dots ----------
__global__ __launch_bounds__(256) void k_heads(
    const float* __restrict__ hsc, const int* __restrict__ row,
    const int* __restrict__ csr, const float* __restrict__ dis,
    const float* __restrict__ W1, const float* __restrict__ b1,
    const float* __restrict__ W2, const float* __restrict__ b2,
    const float* __restrict__ fw1, const float* __restrict__ fb1,
    const float* __restrict__ fw2, const float* __restrict__ fb2,
    float* __restrict__ out) {
    __shared__ float Ws1[D * D], Ws2[D * D];
    for (int k = threadIdx.x; k < D * D; k += 256) { Ws1[k] = W1[k]; Ws2[k] = W2[k]; }
    __syncthreads();
    int t = blockIdx.x * 256 + threadIdx.x;
    int i = t >> 5, f = t & 31;
    if (i >= N_NODES) return;
    float a = hsc[t];
    int rs = row[i], re = row[i + 1];
    for (int j0 = rs; j0 < re; j0 += 16) {
        int sidx = csr[j0 + (f & 15)];
        float v[16];
#pragma unroll
        for (int j = 0; j < 16; ++j) {
            int s = __shfl(sidx, j, 32);
            v[j] = hsc[s * D + f];
        }
#pragma unroll
        for (int j = 0; j < 16; ++j) a += v[j];
    }
    a *= dis[i];
    float a1 = 0.f, a2 = 0.f;
#pragma unroll
    for (int k = 0; k < D; ++k) {
        float ak = __shfl(a, k, 32);
        a1 = fmaf(ak, Ws1[k * D + f], a1);
        a2 = fmaf(ak, Ws2[k * D + f], a2);
    }
    float v1 = a1 + b1[f];
    v1 = (v1 > 0.f ? v1 : 0.f) * fw1[f];
    float v2 = a2 + b2[f];
    v2 = (v2 > 0.f ? v2 : 0.f) * fw2[f];
#pragma unroll
    for (int o = 16; o > 0; o >>= 1) {
        v1 += __shfl_down(v1, o, 32);
        v2 += __shfl_down(v2, o, 32);
    }
    if (f == 0) {
        out[i * 2] = v1 + fb1[0];
        out[i * 2 + 1] = v2 + fb2[0];
    }
}

extern "C" void kernel_launch(void* const* d_in, const int* in_sizes, int n_in,
                              void* d_out, int out_size, void* d_ws, size_t ws_size,
                              hipStream_t stream) {
    const float* x       = (const float*)d_in[0];
    const int*   eidx    = (const int*)d_in[1];
    const float* fc1_w   = (const float*)d_in[2];
    const float* fc1_b   = (const float*)d_in[3];
    const float* conv1_w = (const float*)d_in[4];
    const float* conv1_b = (const float*)d_in[5];
    const float* conv2_w = (const float*)d_in[6];
    const float* conv2_b = (const float*)d_in[7];
    const float* c31_w   = (const float*)d_in[8];
    const float* c31_b   = (const float*)d_in[9];
    const float* c32_w   = (const float*)d_in[10];
    const float* c32_b   = (const float*)d_in[11];
    const float* fc21_w  = (const float*)d_in[12];
    const float* fc21_b  = (const float*)d_in[13];
    const float* fc22_w  = (const float*)d_in[14];
    const float* fc22_b  = (const float*)d_in[15];
    float* out = (float*)d_out;

    const int* src = eidx;            // edge_index[0]
    const int* dst = eidx + N_EDGES;  // edge_index[1]

    // ----- workspace layout (int units; HA/HB 16B-aligned) -----
    int*   wsb   = (int*)d_ws;
    int*   csr   = wsb;                               // CSR_CAP = 4,650,000
    int*   irow  = wsb + 4650000;                     // N+1 (padded region to 150,016)
    int*   ipart = wsb + 4800016;                     // 1024
    int*   ideg  = wsb + 4801040;                     // N
    float* dis   = (float*)(wsb + 4951040);           // N
    float* HA    = (float*)(wsb + 5101040);           // (N+1)*D floats
    float* HB    = (float*)(wsb + 9901072);           // (N+1)*D floats
    int*   ipos  = (int*)HA;                          // E ints, aliases HA (dead before fc1)

    const int BLK = 256;
    const int gN   = (N_NODES + BLK - 1) / BLK;
    const int gND  = (N_NODES * D + BLK - 1) / BLK;
    const int gE   = (N_EDGES + BLK - 1) / BLK;
    const int gCAP = (CSR_CAP + BLK - 1) / BLK;

    // ----- CSR build + normalization -----
    k_zero_int<<<gN, BLK, 0, stream>>>(ideg, N_NODES);
    k_fill_const<<<gCAP, BLK, 0, stream>>>(csr, CSR_CAP, N_NODES);  // pad -> zero row
    k_zero_row<<<1, 32, 0, stream>>>(HA, HB);
    k_count_pos<<<gE, BLK, 0, stream>>>(dst, ideg, ipos);
    k_scan1<<<NBLK_SCAN, SCAN_BLK, 0, stream>>>(ideg, irow, ipart);
    k_scan2<<<1, 1024, 0, stream>>>(ipart, irow);
    k_scan3<<<gN, BLK, 0, stream>>>(ideg, irow, ipart, dis);
    k_fill<<<gE, BLK, 0, stream>>>(src, dst, ipos, irow, csr);

    // ----- network (aggregate-then-transform, fused per layer) -----
    k_fc1<<<gND, BLK, 0, stream>>>(x, fc1_w, fc1_b, dis, HA);
    k_layer<<<gND, BLK, 0, stream>>>(HA, irow, csr, dis, conv1_w, conv1_b, HB);
    k_layer<<<gND, BLK, 0, stream>>>(HB, irow, csr, dis, conv2_w, conv2_b, HA);
    k_heads<<<gND, BLK, 0, stream>>>(HA, irow, csr, dis, c31_w, c31_b, c32_w, c32_b,
                                     fc21_w, fc21_b, fc22_w, fc22_b, out);
}

// Round 6
// 366.920 us; speedup vs baseline: 4.1282x; 1.2274x over previous
//
#include <hip/hip_runtime.h>

#define N_NODES 150000
#define N_EDGES 2400000
#define D 32
#define NBUCK 1172                 // ceil(N/128)
#define CHUNK 4096
#define NCHK 586                   // ceil(E/CHUNK)
#define CSR_CAP (N_EDGES + 15 * N_NODES)

// ---------- zero pad rows of HA/HB (node N_NODES = zero row) ----------
__global__ void k_zero_row(float* __restrict__ HA, float* __restrict__ HB) {
    int t = threadIdx.x;  // 32 threads
    HA[(size_t)N_NODES * D + t] = 0.f;
    HB[(size_t)N_NODES * D + t] = 0.f;
}

// ---------- pass A: per-chunk LDS histogram of buckets ----------
__global__ __launch_bounds__(256) void kA_hist(const int* __restrict__ dst,
                                               int* __restrict__ cnt) {
    __shared__ int bins[NBUCK];
    int t = threadIdx.x;
    for (int k = t; k < NBUCK; k += 256) bins[k] = 0;
    __syncthreads();
    int e0 = blockIdx.x * CHUNK;
#pragma unroll
    for (int r = 0; r < CHUNK / 256; ++r) {
        int e = e0 + r * 256 + t;
        if (e < N_EDGES) atomicAdd(&bins[dst[e] >> 7], 1);
    }
    __syncthreads();
    for (int k = t; k < NBUCK; k += 256) cnt[blockIdx.x * NBUCK + k] = bins[k];
}

// ---------- S1: per-bucket exclusive scan over chunks (tiled, coalesced) ----------
__global__ __launch_bounds__(256) void kS1(int* __restrict__ cnt, int* __restrict__ bstart) {
    __shared__ int tile[8][33];
    __shared__ int carry[32];
    int t = threadIdx.x;
    int tl = t & 31, tr = t >> 5;
    int b = blockIdx.x * 32 + tl;
    if (t < 32) carry[t] = 0;
    __syncthreads();
    for (int c0 = 0; c0 < NCHK; c0 += 8) {
        int c = c0 + tr;
        int v = (c < NCHK && b < NBUCK) ? cnt[c * NBUCK + b] : 0;
        tile[tr][tl] = v;
        __syncthreads();
        if (t < 32) {
            int s = carry[t];
#pragma unroll
            for (int r = 0; r < 8; ++r) { int x = tile[r][t]; tile[r][t] = s; s += x; }
            carry[t] = s;
        }
        __syncthreads();
        if (c < NCHK && b < NBUCK) cnt[c * NBUCK + b] = tile[tr][tl];
        __syncthreads();
    }
    if (t < 32 && b < NBUCK) bstart[b] = carry[t];
}

// ---------- generic single-block exclusive scan in place; a[m] = total ----------
__global__ void k_scan_small(int* __restrict__ a, int m) {
    __shared__ int s[256];
    __shared__ int carry;
    int t = threadIdx.x;
    if (t == 0) carry = 0;
    __syncthreads();
    for (int base = 0; base < m; base += 256) {
        int v = (base + t < m) ? a[base + t] : 0;
        s[t] = v;
        __syncthreads();
        for (int off = 1; off < 256; off <<= 1) {
            int add = (t >= off) ? s[t - off] : 0;
            __syncthreads();
            s[t] += add;
            __syncthreads();
        }
        int c0 = carry;
        if (base + t < m) a[base + t] = c0 + s[t] - v;
        int bsum = s[255];
        __syncthreads();
        if (t == 0) carry = c0 + bsum;
        __syncthreads();
    }
    if (t == 0) a[m] = carry;
}

// ---------- pass B: scatter packed edges into bucket-grouped ebuf ----------
__global__ __launch_bounds__(256) void kB_scatter(const int* __restrict__ src,
                                                  const int* __restrict__ dst,
                                                  const int* __restrict__ cnt,
                                                  const int* __restrict__ bstart,
                                                  int* __restrict__ ebuf) {
    __shared__ int lofs[NBUCK];
    int t = threadIdx.x;
    for (int k = t; k < NBUCK; k += 256)
        lofs[k] = bstart[k] + cnt[blockIdx.x * NBUCK + k];
    __syncthreads();
    int e0 = blockIdx.x * CHUNK;
#pragma unroll
    for (int r = 0; r < CHUNK / 256; ++r) {
        int e = e0 + r * 256 + t;
        if (e < N_EDGES) {
            int d = dst[e];
            int p = atomicAdd(&lofs[d >> 7], 1);
            ebuf[p] = src[e] | ((d & 127) << 18);  // src < 2^18
        }
    }
}

// ---------- C1: per-bucket degree histogram -> deg, dis, padded totals ----------
__global__ __launch_bounds__(256) void kC1(const int* __restrict__ ebuf,
                                           const int* __restrict__ bstart,
                                           int* __restrict__ deg,
                                           float* __restrict__ dis,
                                           int* __restrict__ pbase) {
    __shared__ int hist[128];
    __shared__ int sc[128];
    int b = blockIdx.x, t = threadIdx.x;
    if (t < 128) hist[t] = 0;
    __syncthreads();
    int s0 = bstart[b], s1 = bstart[b + 1];
    for (int e = s0 + t; e < s1; e += 256) atomicAdd(&hist[ebuf[e] >> 18], 1);
    __syncthreads();
    int i = b * 128 + t;
    if (t < 128) {
        int dv = hist[t];
        if (i < N_NODES) {
            deg[i] = dv;
            dis[i] = rsqrtf((float)dv + 1.0f);
        }
        sc[t] = (i < N_NODES) ? ((dv + 15) & ~15) : 0;
    }
    __syncthreads();
    for (int s = 64; s > 0; s >>= 1) {
        if (t < s) sc[t] += sc[t + s];
        __syncthreads();
    }
    if (t == 0) pbase[b] = sc[0];
}

// ---------- C3: per-bucket CSR fill (padded-16 rows) + irow ----------
__global__ __launch_bounds__(256) void kC3(const int* __restrict__ ebuf,
                                           const int* __restrict__ bstart,
                                           const int* __restrict__ deg,
                                           const int* __restrict__ pbase,
                                           int* __restrict__ csr,
                                           int* __restrict__ irow) {
    __shared__ int sc[128];
    __shared__ int loff[128];
    __shared__ int pos[128];
    int b = blockIdx.x, t = threadIdx.x;
    if (b == 0 && t == 0) irow[N_NODES] = pbase[NBUCK];
    int i = b * 128 + t;
    int dv = 0, pad = 0;
    if (t < 128) {
        dv = (i < N_NODES) ? deg[i] : 0;
        pad = (dv + 15) & ~15;
        sc[t] = pad;
        pos[t] = 0;
    }
    __syncthreads();
    for (int off = 1; off < 128; off <<= 1) {
        int add = 0;
        if (t < 128 && t >= off) add = sc[t - off];
        __syncthreads();
        if (t < 128) sc[t] += add;
        __syncthreads();
    }
    int base = pbase[b];
    if (t < 128) {
        loff[t] = sc[t] - pad;  // exclusive prefix
        if (i < N_NODES) irow[i] = base + loff[t];
    }
    __syncthreads();
    int s0 = bstart[b], s1 = bstart[b + 1];
    for (int e = s0 + t; e < s1; e += 256) {
        int v = ebuf[e];
        int dl = v >> 18;
        int p = atomicAdd(&pos[dl], 1);
        csr[base + loff[dl] + p] = v & 0x3FFFF;
    }
    __syncthreads();
    if (t < 128 && i < N_NODES) {
        int st = base + loff[t] + dv, en = base + loff[t] + pad;
        for (int q = st; q < en; ++q) csr[q] = N_NODES;  // pad -> zero row
    }
}

// ---------- pack xd = (x0, x1, dis, 0); row N = zeros ----------
__global__ void k_pack(const float2* __restrict__ x, const float* __restrict__ dis,
                       float4* __restrict__ xd) {
    int i = blockIdx.x * blockDim.x + threadIdx.x;
    if (i < N_NODES) {
        float2 xv = x[i];
        xd[i] = make_float4(xv.x, xv.y, dis[i], 0.f);
    } else if (i == N_NODES) {
        xd[i] = make_float4(0.f, 0.f, 0.f, 0.f);
    }
}

// ---------- layer1 fused with fc1: gather reads 16B xd rows ----------
__global__ __launch_bounds__(256) void k_layer1f(const float4* __restrict__ xd,
                                                 const int* __restrict__ row,
                                                 const int* __restrict__ csr,
                                                 const float* __restrict__ W,   // fc1_w [2][32]
                                                 const float* __restrict__ bf,  // fc1_b
                                                 const float* __restrict__ Wc,  // conv1_w [32][32]
                                                 const float* __restrict__ bc,  // conv1_b
                                                 float* __restrict__ hout) {
    __shared__ float Ws[D * D];
    for (int k = threadIdx.x; k < D * D; k += 256) Ws[k] = Wc[k];
    __syncthreads();
    int t = blockIdx.x * 256 + threadIdx.x;
    int i = t >> 5, f = t & 31;
    if (i >= N_NODES) return;
    float w0 = W[f], w1 = W[D + f], bb = bf[f];
    float4 sv = xd[i];
    float h = fmaf(sv.x, w0, fmaf(sv.y, w1, bb));
    h = h > 0.f ? h : 0.f;
    float a = h * sv.z;  // self-loop (hsc = relu(xW+b)*dis)
    int rs = row[i], re = row[i + 1];
    for (int j0 = rs; j0 < re; j0 += 16) {
        int sidx = csr[j0 + (f & 15)];
        float4 v8[8];
#pragma unroll
        for (int j = 0; j < 8; ++j) { int s = __shfl(sidx, j, 32); v8[j] = xd[s]; }
#pragma unroll
        for (int j = 0; j < 8; ++j) {
            float hh = fmaf(v8[j].x, w0, fmaf(v8[j].y, w1, bb));
            hh = hh > 0.f ? hh : 0.f;
            a = fmaf(hh, v8[j].z, a);
        }
#pragma unroll
        for (int j = 8; j < 16; ++j) { int s = __shfl(sidx, j, 32); v8[j - 8] = xd[s]; }
#pragma unroll
        for (int j = 0; j < 8; ++j) {
            float hh = fmaf(v8[j].x, w0, fmaf(v8[j].y, w1, bb));
            hh = hh > 0.f ? hh : 0.f;
            a = fmaf(hh, v8[j].z, a);
        }
    }
    float di = sv.z;
    a *= di;
    float acc = 0.f;
#pragma unroll
    for (int k = 0; k < D; ++k) {
        float ak = __shfl(a, k, 32);
        acc = fmaf(ak, Ws[k * D + f], acc);
    }
    float v = acc + bc[f];
    v = v > 0.f ? v : 0.f;
    hout[t] = v * di;
}

// ---------- fused layer: hout = relu((dis_i * Σ hsc[s]) @ W + b) * dis_i ----------
__global__ __launch_bounds__(256) void k_layer(const float* __restrict__ hsc,
                                               const int* __restrict__ row,
                                               const int* __restrict__ csr,
                                               const float* __restrict__ dis,
                                               const float* __restrict__ W,
                                               const float* __restrict__ b,
                                               float* __restrict__ hout) {
    __shared__ float Ws[D * D];
    for (int k = threadIdx.x; k < D * D; k += 256) Ws[k] = W[k];
    __syncthreads();
    int t = blockIdx.x * 256 + threadIdx.x;
    int i = t >> 5, f = t & 31;
    if (i >= N_NODES) return;
    float a = hsc[t];  // self-loop
    int rs = row[i], re = row[i + 1];
    for (int j0 = rs; j0 < re; j0 += 16) {
        int sidx = csr[j0 + (f & 15)];
        float v[16];
#pragma unroll
        for (int j = 0; j < 16; ++j) {
            int s = __shfl(sidx, j, 32);
            v[j] = hsc[s * D + f];
        }
#pragma unroll
        for (int j = 0; j < 16; ++j) a += v[j];
    }
    float di = dis[i];
    a *= di;
    float acc = 0.f;
#pragma unroll
    for (int k = 0; k < D; ++k) {
        float ak = __shfl(a, k, 32);
        acc = fmaf(ak, Ws[k * D + f], acc);
    }
    float v = acc + b[f];
    v = v > 0.f ? v : 0.f;
    hout[t] = v * di;
}

// ---------- heads: one gather, two transforms + relu + 32->1 dots ----------
__global__ __launch_bounds__(256) void k_heads(
    const float* __restrict__ hsc, const int* __restrict__ row,
    const int* __restrict__ csr, const float* __restrict__ dis,
    const float* __restrict__ W1, const float* __restrict__ b1,
    const float* __restrict__ W2, const float* __restrict__ b2,
    const float* __restrict__ fw1, const float* __restrict__ fb1,
    const float* __restrict__ fw2, const float* __restrict__ fb2,
    float* __restrict__ out) {
    __shared__ float Ws1[D * D], Ws2[D * D];
    for (int k = threadIdx.x; k < D * D; k += 256) { Ws1[k] = W1[k]; Ws2[k] = W2[k]; }
    __syncthreads();
    int t = blockIdx.x * 256 + threadIdx.x;
    int i = t >> 5, f = t & 31;
    if (i >= N_NODES) return;
    float a = hsc[t];
    int rs = row[i], re = row[i + 1];
    for (int j0 = rs; j0 < re; j0 += 16) {
        int sidx = csr[j0 + (f & 15)];
        float v[16];
#pragma unroll
        for (int j = 0; j < 16; ++j) {
            int s = __shfl(sidx, j, 32);
            v[j] = hsc[s * D + f];
        }
#pragma unroll
        for (int j = 0; j < 16; ++j) a += v[j];
    }
    a *= dis[i];
    float a1 = 0.f, a2 = 0.f;
#pragma unroll
    for (int k = 0; k < D; ++k) {
        float ak = __shfl(a, k, 32);
        a1 = fmaf(ak, Ws1[k * D + f], a1);
        a2 = fmaf(ak, Ws2[k * D + f], a2);
    }
    float v1 = a1 + b1[f];
    v1 = (v1 > 0.f ? v1 : 0.f) * fw1[f];
    float v2 = a2 + b2[f];
    v2 = (v2 > 0.f ? v2 : 0.f) * fw2[f];
#pragma unroll
    for (int o = 16; o > 0; o >>= 1) {
        v1 += __shfl_down(v1, o, 32);
        v2 += __shfl_down(v2, o, 32);
    }
    if (f == 0) {
        out[i * 2] = v1 + fb1[0];
        out[i * 2 + 1] = v2 + fb2[0];
    }
}

extern "C" void kernel_launch(void* const* d_in, const int* in_sizes, int n_in,
                              void* d_out, int out_size, void* d_ws, size_t ws_size,
                              hipStream_t stream) {
    const float* x       = (const float*)d_in[0];
    const int*   eidx    = (const int*)d_in[1];
    const float* fc1_w   = (const float*)d_in[2];
    const float* fc1_b   = (const float*)d_in[3];
    const float* conv1_w = (const float*)d_in[4];
    const float* conv1_b = (const float*)d_in[5];
    const float* conv2_w = (const float*)d_in[6];
    const float* conv2_b = (const float*)d_in[7];
    const float* c31_w   = (const float*)d_in[8];
    const float* c31_b   = (const float*)d_in[9];
    const float* c32_w   = (const float*)d_in[10];
    const float* c32_b   = (const float*)d_in[11];
    const float* fc21_w  = (const float*)d_in[12];
    const float* fc21_b  = (const float*)d_in[13];
    const float* fc22_w  = (const float*)d_in[14];
    const float* fc22_b  = (const float*)d_in[15];
    float* out = (float*)d_out;

    const int* src = eidx;            // edge_index[0]
    const int* dst = eidx + N_EDGES;  // edge_index[1]

    // ----- workspace layout (int units) -----
    int*   wsb    = (int*)d_ws;
    int*   csr    = wsb;                       // 4,650,000
    int*   irow   = wsb + 4650000;             // 150,016
    int*   bstart = wsb + 4800016;             // 1,184 (NBUCK+1 used)
    int*   pbase  = wsb + 4801200;             // 1,184
    float* dis    = (float*)(wsb + 4802384);   // 150,000 -> end 4,952,384
    float* HA     = (float*)(wsb + 4952384);   // 4,800,032 -> end 9,752,416
    float* HB     = (float*)(wsb + 9752416);   // 4,800,032 -> end 14,552,448
    // transient aliases inside HA (dead before conv2 writes HA):
    int*   cnt    = (int*)HA;                  // 686,792
    int*   ebuf   = (int*)HA + 700000;         // 2,400,000 -> rel end 3,100,000
    float4* xd    = (float4*)((int*)HA + 3100016);  // 600,064 floats, 16B aligned
    // deg aliases HB low (dead before k_layer1f writes HB):
    int*   deg    = (int*)HB;                  // 150,000

    const int BLK = 256;
    const int gL  = (N_NODES * D + BLK - 1) / BLK;  // 18750

    // ----- CSR build (no global atomics) -----
    k_zero_row<<<1, 32, 0, stream>>>(HA, HB);
    kA_hist<<<NCHK, BLK, 0, stream>>>(dst, cnt);
    kS1<<<(NBUCK + 31) / 32, BLK, 0, stream>>>(cnt, bstart);
    k_scan_small<<<1, BLK, 0, stream>>>(bstart, NBUCK);
    kB_scatter<<<NCHK, BLK, 0, stream>>>(src, dst, cnt, bstart, ebuf);
    kC1<<<NBUCK, BLK, 0, stream>>>(ebuf, bstart, deg, dis, pbase);
    k_scan_small<<<1, BLK, 0, stream>>>(pbase, NBUCK);
    kC3<<<NBUCK, BLK, 0, stream>>>(ebuf, bstart, deg, pbase, csr, irow);

    // ----- network -----
    k_pack<<<(N_NODES + 1 + BLK - 1) / BLK, BLK, 0, stream>>>((const float2*)x, dis, xd);
    k_layer1f<<<gL, BLK, 0, stream>>>(xd, irow, csr, fc1_w, fc1_b, conv1_w, conv1_b, HB);
    k_layer<<<gL, BLK, 0, stream>>>(HB, irow, csr, dis, conv2_w, conv2_b, HA);
    k_heads<<<gL, BLK, 0, stream>>>(HA, irow, csr, dis, c31_w, c31_b, c32_w, c32_b,
                                    fc21_w, fc21_b, fc22_w, fc22_b, out);
}

// Round 7
// 352.216 us; speedup vs baseline: 4.3005x; 1.0417x over previous
//
#include <hip/hip_runtime.h>

#define N_NODES 150000
#define N_EDGES 2400000
#define D 32
#define NBUCK 1172                 // ceil(N/128)
#define CHUNK 4096
#define NCHK 586                   // ceil(E/CHUNK)
#define CSR_CAP (N_EDGES + 3 * N_NODES + 64)

// ---------- zero pad rows of HA/HB (node N_NODES = zero row) ----------
__global__ void k_zero_row(float* __restrict__ HA, float* __restrict__ HB) {
    int t = threadIdx.x;  // 32 threads
    HA[(size_t)N_NODES * D + t] = 0.f;
    HB[(size_t)N_NODES * D + t] = 0.f;
}

// ---------- pass A: per-chunk LDS histogram of buckets ----------
__global__ __launch_bounds__(256) void kA_hist(const int* __restrict__ dst,
                                               int* __restrict__ cnt) {
    __shared__ int bins[NBUCK];
    int t = threadIdx.x;
    for (int k = t; k < NBUCK; k += 256) bins[k] = 0;
    __syncthreads();
    int e0 = blockIdx.x * CHUNK;
#pragma unroll
    for (int r = 0; r < CHUNK / 256; ++r) {
        int e = e0 + r * 256 + t;
        if (e < N_EDGES) atomicAdd(&bins[dst[e] >> 7], 1);
    }
    __syncthreads();
    for (int k = t; k < NBUCK; k += 256) cnt[blockIdx.x * NBUCK + k] = bins[k];
}

// ---------- S1: per-bucket exclusive scan over chunks ----------
__global__ __launch_bounds__(256) void kS1(int* __restrict__ cnt, int* __restrict__ bstart) {
    __shared__ int tile[8][33];
    __shared__ int carry[32];
    int t = threadIdx.x;
    int tl = t & 31, tr = t >> 5;
    int b = blockIdx.x * 32 + tl;
    if (t < 32) carry[t] = 0;
    __syncthreads();
    for (int c0 = 0; c0 < NCHK; c0 += 8) {
        int c = c0 + tr;
        int v = (c < NCHK && b < NBUCK) ? cnt[c * NBUCK + b] : 0;
        tile[tr][tl] = v;
        __syncthreads();
        if (t < 32) {
            int s = carry[t];
#pragma unroll
            for (int r = 0; r < 8; ++r) { int x = tile[r][t]; tile[r][t] = s; s += x; }
            carry[t] = s;
        }
        __syncthreads();
        if (c < NCHK && b < NBUCK) cnt[c * NBUCK + b] = tile[tr][tl];
        __syncthreads();
    }
    if (t < 32 && b < NBUCK) bstart[b] = carry[t];
}

// ---------- single-block exclusive scan in place; a[m] = total ----------
__global__ void k_scan_small(int* __restrict__ a, int m) {
    __shared__ int s[256];
    __shared__ int carry;
    int t = threadIdx.x;
    if (t == 0) carry = 0;
    __syncthreads();
    for (int base = 0; base < m; base += 256) {
        int v = (base + t < m) ? a[base + t] : 0;
        s[t] = v;
        __syncthreads();
        for (int off = 1; off < 256; off <<= 1) {
            int add = (t >= off) ? s[t - off] : 0;
            __syncthreads();
            s[t] += add;
            __syncthreads();
        }
        int c0 = carry;
        if (base + t < m) a[base + t] = c0 + s[t] - v;
        int bsum = s[255];
        __syncthreads();
        if (t == 0) carry = c0 + bsum;
        __syncthreads();
    }
    if (t == 0) a[m] = carry;
}

// ---------- pass B: scatter packed edges into bucket-grouped ebuf ----------
__global__ __launch_bounds__(256) void kB_scatter(const int* __restrict__ src,
                                                  const int* __restrict__ dst,
                                                  const int* __restrict__ cnt,
                                                  const int* __restrict__ bstart,
                                                  int* __restrict__ ebuf) {
    __shared__ int lofs[NBUCK];
    int t = threadIdx.x;
    for (int k = t; k < NBUCK; k += 256)
        lofs[k] = bstart[k] + cnt[blockIdx.x * NBUCK + k];
    __syncthreads();
    int e0 = blockIdx.x * CHUNK;
#pragma unroll
    for (int r = 0; r < CHUNK / 256; ++r) {
        int e = e0 + r * 256 + t;
        if (e < N_EDGES) {
            int d = dst[e];
            int p = atomicAdd(&lofs[d >> 7], 1);
            ebuf[p] = src[e] | ((d & 127) << 18);  // src < 2^18
        }
    }
}

// ---------- C1: per-bucket degree histogram -> deg, dis, xd, padded totals ----------
__global__ __launch_bounds__(256) void kC1(const int* __restrict__ ebuf,
                                           const int* __restrict__ bstart,
                                           const float2* __restrict__ x,
                                           int* __restrict__ deg,
                                           float* __restrict__ dis,
                                           float4* __restrict__ xd,
                                           int* __restrict__ pbase) {
    __shared__ int hist[128];
    __shared__ int sc[128];
    int b = blockIdx.x, t = threadIdx.x;
    if (t < 128) hist[t] = 0;
    __syncthreads();
    int s0 = bstart[b], s1 = bstart[b + 1];
    for (int e = s0 + t; e < s1; e += 256) atomicAdd(&hist[ebuf[e] >> 18], 1);
    __syncthreads();
    int i = b * 128 + t;
    if (t < 128) {
        int dv = hist[t];
        if (i < N_NODES) {
            deg[i] = dv;
            float dz = rsqrtf((float)dv + 1.0f);
            dis[i] = dz;
            float2 xv = x[i];
            xd[i] = make_float4(xv.x, xv.y, dz, 0.f);
        } else if (i == N_NODES) {
            xd[i] = make_float4(0.f, 0.f, 0.f, 0.f);
        }
        sc[t] = (i < N_NODES) ? ((dv + 3) & ~3) : 0;  // pad-4
    }
    __syncthreads();
    for (int s = 64; s > 0; s >>= 1) {
        if (t < s) sc[t] += sc[t + s];
        __syncthreads();
    }
    if (t == 0) pbase[b] = sc[0];
}

// ---------- C3: per-bucket CSR fill (pad-4 rows) + irow + end slack ----------
__global__ __launch_bounds__(256) void kC3(const int* __restrict__ ebuf,
                                           const int* __restrict__ bstart,
                                           const int* __restrict__ deg,
                                           const int* __restrict__ pbase,
                                           int* __restrict__ csr,
                                           int* __restrict__ irow) {
    __shared__ int sc[128];
    __shared__ int loff[128];
    __shared__ int pos[128];
    int b = blockIdx.x, t = threadIdx.x;
    if (b == 0) {
        if (t == 0) irow[N_NODES] = pbase[NBUCK];
        if (t < 64) csr[pbase[NBUCK] + t] = N_NODES;  // slack for 16-wide csr reads
    }
    int i = b * 128 + t;
    int dv = 0, pad = 0;
    if (t < 128) {
        dv = (i < N_NODES) ? deg[i] : 0;
        pad = (dv + 3) & ~3;
        sc[t] = pad;
        pos[t] = 0;
    }
    __syncthreads();
    for (int off = 1; off < 128; off <<= 1) {
        int add = 0;
        if (t < 128 && t >= off) add = sc[t - off];
        __syncthreads();
        if (t < 128) sc[t] += add;
        __syncthreads();
    }
    int base = pbase[b];
    if (t < 128) {
        loff[t] = sc[t] - pad;  // exclusive prefix
        if (i < N_NODES) irow[i] = base + loff[t];
    }
    __syncthreads();
    int s0 = bstart[b], s1 = bstart[b + 1];
    for (int e = s0 + t; e < s1; e += 256) {
        int v = ebuf[e];
        int dl = v >> 18;
        int p = atomicAdd(&pos[dl], 1);
        csr[base + loff[dl] + p] = v & 0x3FFFF;
    }
    __syncthreads();
    if (t < 128 && i < N_NODES) {
        int st = base + loff[t] + dv, en = base + loff[t] + pad;
        for (int q = st; q < en; ++q) csr[q] = N_NODES;  // pad -> zero row
    }
}

// ---------- layer1 fused with fc1: per-lane 16B gather + shfl MLP ----------
__global__ __launch_bounds__(256) void k_layer1f(const float4* __restrict__ xd,
                                                 const int* __restrict__ row,
                                                 const int* __restrict__ csr,
                                                 const float* __restrict__ W,   // fc1_w [2][32]
                                                 const float* __restrict__ bf,  // fc1_b
                                                 const float* __restrict__ Wc,  // conv1_w
                                                 const float* __restrict__ bc,  // conv1_b
                                                 float* __restrict__ hout) {
    __shared__ float Ws[D * D];
    for (int k = threadIdx.x; k < D * D; k += 256) Ws[k] = Wc[k];
    __syncthreads();
    int t = blockIdx.x * 256 + threadIdx.x;
    int i = t >> 5;
    if (i >= N_NODES) return;
    int l = threadIdx.x & 31, f = l;
    float w0 = W[f], w1 = W[D + f], bb = bf[f];
    float4 sv = xd[i];
    float hs = fmaf(sv.x, w0, fmaf(sv.y, w1, bb));
    hs = hs > 0.f ? hs : 0.f;
    float a = hs * sv.z;  // self-loop
    int rs = row[i], re = row[i + 1];
    for (int j0 = rs; j0 < re; j0 += 16) {
        int slot = j0 + (l & 15);
        int sidx = csr[slot];
        sidx = (slot < re) ? sidx : N_NODES;  // sanitize for per-lane load
        float4 v = xd[sidx];  // 16 distinct 16B rows in ONE instruction
#pragma unroll
        for (int it = 0; it < 4; ++it) {
            if (j0 + it * 4 >= re) break;  // rows are pad-4; uniform per group
#pragma unroll
            for (int q = it * 4; q < it * 4 + 4; ++q) {
                float x0 = __shfl(v.x, q, 32);
                float x1 = __shfl(v.y, q, 32);
                float dz = __shfl(v.z, q, 32);
                float h2 = fmaf(x0, w0, fmaf(x1, w1, bb));
                h2 = h2 > 0.f ? h2 : 0.f;
                a = fmaf(h2, dz, a);
            }
        }
    }
    float di = sv.z;
    a *= di;
    float acc = 0.f;
#pragma unroll
    for (int k = 0; k < D; ++k)
        acc = fmaf(__shfl(a, k, 32), Ws[k * D + f], acc);
    float v = acc + bc[f];
    v = v > 0.f ? v : 0.f;
    hout[t] = v * di;
}

// ---------- fused layer: 4-neighbor × float4 gather + transform ----------
__global__ __launch_bounds__(256) void k_layer(const float* __restrict__ hsc,
                                               const int* __restrict__ row,
                                               const int* __restrict__ csr,
                                               const float* __restrict__ dis,
                                               const float* __restrict__ W,
                                               const float* __restrict__ b,
                                               float* __restrict__ hout) {
    __shared__ float Ws[D * D];
    for (int k = threadIdx.x; k < D * D; k += 256) Ws[k] = W[k];
    __syncthreads();
    int t = blockIdx.x * 256 + threadIdx.x;
    int i = t >> 5;
    if (i >= N_NODES) return;
    int l = threadIdx.x & 31;
    int c = l & 7;  // float4 chunk of the row
    const float4* rowf4 = (const float4*)hsc;
    float4 a4 = make_float4(0.f, 0.f, 0.f, 0.f);
    int rs = row[i], re = row[i + 1];
    for (int j0 = rs; j0 < re; j0 += 16) {
        int sidx = csr[j0 + (l & 15)];
#pragma unroll
        for (int it = 0; it < 4; ++it) {
            if (j0 + it * 4 >= re) break;  // pad-4 rows; uniform per group
            int s = __shfl(sidx, it * 4 + (l >> 3), 32);
            float4 v = rowf4[s * 8 + c];  // 4 full rows (512B) per instruction
            a4.x += v.x; a4.y += v.y; a4.z += v.z; a4.w += v.w;
        }
    }
    // reduce across the 4 neighbor-groups (once per node)
    a4.x += __shfl_xor(a4.x, 8, 32);  a4.y += __shfl_xor(a4.y, 8, 32);
    a4.z += __shfl_xor(a4.z, 8, 32);  a4.w += __shfl_xor(a4.w, 8, 32);
    a4.x += __shfl_xor(a4.x, 16, 32); a4.y += __shfl_xor(a4.y, 16, 32);
    a4.z += __shfl_xor(a4.z, 16, 32); a4.w += __shfl_xor(a4.w, 16, 32);
    float4 sv = rowf4[i * 8 + c];  // self row
    a4.x += sv.x; a4.y += sv.y; a4.z += sv.z; a4.w += sv.w;
    float di = dis[i];
    a4.x *= di; a4.y *= di; a4.z *= di; a4.w *= di;
    // transform: feature k = q*4+m lives in lane q, component m
    int f = l;
    float acc = 0.f;
#pragma unroll
    for (int q = 0; q < 8; ++q) {
        acc = fmaf(__shfl(a4.x, q, 32), Ws[(q * 4 + 0) * D + f], acc);
        acc = fmaf(__shfl(a4.y, q, 32), Ws[(q * 4 + 1) * D + f], acc);
        acc = fmaf(__shfl(a4.z, q, 32), Ws[(q * 4 + 2) * D + f], acc);
        acc = fmaf(__shfl(a4.w, q, 32), Ws[(q * 4 + 3) * D + f], acc);
    }
    float v = acc + b[f];
    v = v > 0.f ? v : 0.f;
    hout[t] = v * di;
}

// ---------- heads: same gather, two transforms + relu + 32->1 dots ----------
__global__ __launch_bounds__(256) void k_heads(
    const float* __restrict__ hsc, const int* __restrict__ row,
    const int* __restrict__ csr, const float* __restrict__ dis,
    const float* __restrict__ W1, const float* __restrict__ b1,
    const float* __restrict__ W2, const float* __restrict__ b2,
    const float* __restrict__ fw1, const float* __restrict__ fb1,
    const float* __restrict__ fw2, const float* __restrict__ fb2,
    float* __restrict__ out) {
    __shared__ float Ws1[D * D], Ws2[D * D];
    for (int k = threadIdx.x; k < D * D; k += 256) { Ws1[k] = W1[k]; Ws2[k] = W2[k]; }
    __syncthreads();
    int t = blockIdx.x * 256 + threadIdx.x;
    int i = t >> 5;
    if (i >= N_NODES) return;
    int l = threadIdx.x & 31;
    int c = l & 7;
    const float4* rowf4 = (const float4*)hsc;
    float4 a4 = make_float4(0.f, 0.f, 0.f, 0.f);
    int rs = row[i], re = row[i + 1];
    for (int j0 = rs; j0 < re; j0 += 16) {
        int sidx = csr[j0 + (l & 15)];
#pragma unroll
        for (int it = 0; it < 4; ++it) {
            if (j0 + it * 4 >= re) break;
            int s = __shfl(sidx, it * 4 + (l >> 3), 32);
            float4 v = rowf4[s * 8 + c];
            a4.x += v.x; a4.y += v.y; a4.z += v.z; a4.w += v.w;
        }
    }
    a4.x += __shfl_xor(a4.x, 8, 32);  a4.y += __shfl_xor(a4.y, 8, 32);
    a4.z += __shfl_xor(a4.z, 8, 32);  a4.w += __shfl_xor(a4.w, 8, 32);
    a4.x += __shfl_xor(a4.x, 16, 32); a4.y += __shfl_xor(a4.y, 16, 32);
    a4.z += __shfl_xor(a4.z, 16, 32); a4.w += __shfl_xor(a4.w, 16, 32);
    float4 sv = rowf4[i * 8 + c];
    a4.x += sv.x; a4.y += sv.y; a4.z += sv.z; a4.w += sv.w;
    float di = dis[i];
    a4.x *= di; a4.y *= di; a4.z *= di; a4.w *= di;
    int f = l;
    float acc1 = 0.f, acc2 = 0.f;
#pragma unroll
    for (int q = 0; q < 8; ++q) {
        float ak;
        ak = __shfl(a4.x, q, 32);
        acc1 = fmaf(ak, Ws1[(q * 4 + 0) * D + f], acc1);
        acc2 = fmaf(ak, Ws2[(q * 4 + 0) * D + f], acc2);
        ak = __shfl(a4.y, q, 32);
        acc1 = fmaf(ak, Ws1[(q * 4 + 1) * D + f], acc1);
        acc2 = fmaf(ak, Ws2[(q * 4 + 1) * D + f], acc2);
        ak = __shfl(a4.z, q, 32);
        acc1 = fmaf(ak, Ws1[(q * 4 + 2) * D + f], acc1);
        acc2 = fmaf(ak, Ws2[(q * 4 + 2) * D + f], acc2);
        ak = __shfl(a4.w, q, 32);
        acc1 = fmaf(ak, Ws1[(q * 4 + 3) * D + f], acc1);
        acc2 = fmaf(ak, Ws2[(q * 4 + 3) * D + f], acc2);
    }
    float v1 = acc1 + b1[f];
    v1 = (v1 > 0.f ? v1 : 0.f) * fw1[f];
    float v2 = acc2 + b2[f];
    v2 = (v2 > 0.f ? v2 : 0.f) * fw2[f];
#pragma unroll
    for (int o = 16; o > 0; o >>= 1) {
        v1 += __shfl_down(v1, o, 32);
        v2 += __shfl_down(v2, o, 32);
    }
    if (f == 0) {
        out[i * 2] = v1 + fb1[0];
        out[i * 2 + 1] = v2 + fb2[0];
    }
}

extern "C" void kernel_launch(void* const* d_in, const int* in_sizes, int n_in,
                              void* d_out, int out_size, void* d_ws, size_t ws_size,
                              hipStream_t stream) {
    const float* x       = (const float*)d_in[0];
    const int*   eidx    = (const int*)d_in[1];
    const float* fc1_w   = (const float*)d_in[2];
    const float* fc1_b   = (const float*)d_in[3];
    const float* conv1_w = (const float*)d_in[4];
    const float* conv1_b = (const float*)d_in[5];
    const float* conv2_w = (const float*)d_in[6];
    const float* conv2_b = (const float*)d_in[7];
    const float* c31_w   = (const float*)d_in[8];
    const float* c31_b   = (const float*)d_in[9];
    const float* c32_w   = (const float*)d_in[10];
    const float* c32_b   = (const float*)d_in[11];
    const float* fc21_w  = (const float*)d_in[12];
    const float* fc21_b  = (const float*)d_in[13];
    const float* fc22_w  = (const float*)d_in[14];
    const float* fc22_b  = (const float*)d_in[15];
    float* out = (float*)d_out;

    const int* src = eidx;            // edge_index[0]
    const int* dst = eidx + N_EDGES;  // edge_index[1]

    // ----- workspace layout (int units; 16B alignment preserved) -----
    int*   wsb    = (int*)d_ws;
    int*   csr    = wsb;                        // CSR_CAP = 2,850,064
    int*   irow   = wsb + 2850064;              // 150,004
    int*   bstart = wsb + 3000068;              // 1,174
    int*   pbase  = wsb + 3001242;              // 1,174
    float* dis    = (float*)(wsb + 3002416);    // 150,000
    float* HA     = (float*)(wsb + 3152416);    // 4,800,032 floats
    float* HB     = (float*)(wsb + 7952448);    // 4,800,032 floats
    // transient aliases inside HA (dead before k_layer writes HA):
    int*    cnt  = (int*)HA;                    // 686,792
    int*    ebuf = (int*)HA + 700000;           // 2,400,000
    float4* xd   = (float4*)((int*)HA + 3100016);  // (N+1) float4
    // deg aliases HB low (dead before k_layer1f writes HB):
    int*    deg  = (int*)HB;                    // 150,000

    const int BLK = 256;
    const int gL  = (N_NODES * D + BLK - 1) / BLK;  // 18750

    // ----- CSR build (no global atomics) -----
    k_zero_row<<<1, 32, 0, stream>>>(HA, HB);
    kA_hist<<<NCHK, BLK, 0, stream>>>(dst, cnt);
    kS1<<<(NBUCK + 31) / 32, BLK, 0, stream>>>(cnt, bstart);
    k_scan_small<<<1, BLK, 0, stream>>>(bstart, NBUCK);
    kB_scatter<<<NCHK, BLK, 0, stream>>>(src, dst, cnt, bstart, ebuf);
    kC1<<<NBUCK, BLK, 0, stream>>>(ebuf, bstart, (const float2*)x, deg, dis, xd, pbase);
    k_scan_small<<<1, BLK, 0, stream>>>(pbase, NBUCK);
    kC3<<<NBUCK, BLK, 0, stream>>>(ebuf, bstart, deg, pbase, csr, irow);

    // ----- network -----
    k_layer1f<<<gL, BLK, 0, stream>>>(xd, irow, csr, fc1_w, fc1_b, conv1_w, conv1_b, HB);
    k_layer<<<gL, BLK, 0, stream>>>(HB, irow, csr, dis, conv2_w, conv2_b, HA);
    k_heads<<<gL, BLK, 0, stream>>>(HA, irow, csr, dis, c31_w, c31_b, c32_w, c32_b,
                                    fc21_w, fc21_b, fc22_w, fc22_b, out);
}

// Round 8
// 302.583 us; speedup vs baseline: 5.0059x; 1.1640x over previous
//
#include <hip/hip_runtime.h>

#define N_NODES 150000
#define N_EDGES 2400000
#define D 32
#define NBUCK 1172                 // ceil(N/128)
#define CHUNK 4096
#define NCHK 586                   // ceil(E/CHUNK)
#define CSR_CAP (N_EDGES + 3 * N_NODES + 64)

// ---------- zero pad rows of HA/HB (node N_NODES = zero row) ----------
__global__ void k_zero_row(float* __restrict__ HA, float* __restrict__ HB) {
    int t = threadIdx.x;  // 32 threads
    HA[(size_t)N_NODES * D + t] = 0.f;
    HB[(size_t)N_NODES * D + t] = 0.f;
}

// ---------- pass A: per-chunk LDS histogram of buckets ----------
__global__ __launch_bounds__(256) void kA_hist(const int* __restrict__ dst,
                                               int* __restrict__ cnt) {
    __shared__ int bins[NBUCK];
    int t = threadIdx.x;
    for (int k = t; k < NBUCK; k += 256) bins[k] = 0;
    __syncthreads();
    int e0 = blockIdx.x * CHUNK;
#pragma unroll
    for (int r = 0; r < CHUNK / 256; ++r) {
        int e = e0 + r * 256 + t;
        if (e < N_EDGES) atomicAdd(&bins[dst[e] >> 7], 1);
    }
    __syncthreads();
    for (int k = t; k < NBUCK; k += 256) cnt[blockIdx.x * NBUCK + k] = bins[k];
}

// ---------- S1: per-bucket exclusive scan over chunks ----------
__global__ __launch_bounds__(256) void kS1(int* __restrict__ cnt, int* __restrict__ bstart) {
    __shared__ int tile[8][33];
    __shared__ int carry[32];
    int t = threadIdx.x;
    int tl = t & 31, tr = t >> 5;
    int b = blockIdx.x * 32 + tl;
    if (t < 32) carry[t] = 0;
    __syncthreads();
    for (int c0 = 0; c0 < NCHK; c0 += 8) {
        int c = c0 + tr;
        int v = (c < NCHK && b < NBUCK) ? cnt[c * NBUCK + b] : 0;
        tile[tr][tl] = v;
        __syncthreads();
        if (t < 32) {
            int s = carry[t];
#pragma unroll
            for (int r = 0; r < 8; ++r) { int x = tile[r][t]; tile[r][t] = s; s += x; }
            carry[t] = s;
        }
        __syncthreads();
        if (c < NCHK && b < NBUCK) cnt[c * NBUCK + b] = tile[tr][tl];
        __syncthreads();
    }
    if (t < 32 && b < NBUCK) bstart[b] = carry[t];
}

// ---------- single-block exclusive scan in place; a[m] = total ----------
__global__ void k_scan_small(int* __restrict__ a, int m) {
    __shared__ int s[256];
    __shared__ int carry;
    int t = threadIdx.x;
    if (t == 0) carry = 0;
    __syncthreads();
    for (int base = 0; base < m; base += 256) {
        int v = (base + t < m) ? a[base + t] : 0;
        s[t] = v;
        __syncthreads();
        for (int off = 1; off < 256; off <<= 1) {
            int add = (t >= off) ? s[t - off] : 0;
            __syncthreads();
            s[t] += add;
            __syncthreads();
        }
        int c0 = carry;
        if (base + t < m) a[base + t] = c0 + s[t] - v;
        int bsum = s[255];
        __syncthreads();
        if (t == 0) carry = c0 + bsum;
        __syncthreads();
    }
    if (t == 0) a[m] = carry;
}

// ---------- pass B: scatter packed edges into bucket-grouped ebuf ----------
__global__ __launch_bounds__(256) void kB_scatter(const int* __restrict__ src,
                                                  const int* __restrict__ dst,
                                                  const int* __restrict__ cnt,
                                                  const int* __restrict__ bstart,
                                                  int* __restrict__ ebuf) {
    __shared__ int lofs[NBUCK];
    int t = threadIdx.x;
    for (int k = t; k < NBUCK; k += 256)
        lofs[k] = bstart[k] + cnt[blockIdx.x * NBUCK + k];
    __syncthreads();
    int e0 = blockIdx.x * CHUNK;
#pragma unroll
    for (int r = 0; r < CHUNK / 256; ++r) {
        int e = e0 + r * 256 + t;
        if (e < N_EDGES) {
            int d = dst[e];
            int p = atomicAdd(&lofs[d >> 7], 1);
            ebuf[p] = src[e] | ((d & 127) << 18);  // src < 2^18
        }
    }
}

// ---------- C1: per-bucket degree histogram -> deg, dis, xd, padded totals ----------
__global__ __launch_bounds__(256) void kC1(const int* __restrict__ ebuf,
                                           const int* __restrict__ bstart,
                                           const float2* __restrict__ x,
                                           int* __restrict__ deg,
                                           float* __restrict__ dis,
                                           float4* __restrict__ xd,
                                           int* __restrict__ pbase) {
    __shared__ int hist[128];
    __shared__ int sc[128];
    int b = blockIdx.x, t = threadIdx.x;
    if (t < 128) hist[t] = 0;
    __syncthreads();
    int s0 = bstart[b], s1 = bstart[b + 1];
    for (int e = s0 + t; e < s1; e += 256) atomicAdd(&hist[ebuf[e] >> 18], 1);
    __syncthreads();
    int i = b * 128 + t;
    if (t < 128) {
        int dv = hist[t];
        if (i < N_NODES) {
            deg[i] = dv;
            float dz = rsqrtf((float)dv + 1.0f);
            dis[i] = dz;
            float2 xv = x[i];
            xd[i] = make_float4(xv.x, xv.y, dz, 0.f);
        } else if (i == N_NODES) {
            xd[i] = make_float4(0.f, 0.f, 0.f, 0.f);
        }
        sc[t] = (i < N_NODES) ? ((dv + 3) & ~3) : 0;  // pad-4
    }
    __syncthreads();
    for (int s = 64; s > 0; s >>= 1) {
        if (t < s) sc[t] += sc[t + s];
        __syncthreads();
    }
    if (t == 0) pbase[b] = sc[0];
}

// ---------- C3: per-bucket CSR fill (pad-4 rows) + irow + end slack ----------
__global__ __launch_bounds__(256) void kC3(const int* __restrict__ ebuf,
                                           const int* __restrict__ bstart,
                                           const int* __restrict__ deg,
                                           const int* __restrict__ pbase,
                                           int* __restrict__ csr,
                                           int* __restrict__ irow) {
    __shared__ int sc[128];
    __shared__ int loff[128];
    __shared__ int pos[128];
    int b = blockIdx.x, t = threadIdx.x;
    if (b == 0) {
        if (t == 0) irow[N_NODES] = pbase[NBUCK];
        if (t < 64) csr[pbase[NBUCK] + t] = N_NODES;  // slack for 16-wide reads + prefetch
    }
    int i = b * 128 + t;
    int dv = 0, pad = 0;
    if (t < 128) {
        dv = (i < N_NODES) ? deg[i] : 0;
        pad = (dv + 3) & ~3;
        sc[t] = pad;
        pos[t] = 0;
    }
    __syncthreads();
    for (int off = 1; off < 128; off <<= 1) {
        int add = 0;
        if (t < 128 && t >= off) add = sc[t - off];
        __syncthreads();
        if (t < 128) sc[t] += add;
        __syncthreads();
    }
    int base = pbase[b];
    if (t < 128) {
        loff[t] = sc[t] - pad;  // exclusive prefix
        if (i < N_NODES) irow[i] = base + loff[t];
    }
    __syncthreads();
    int s0 = bstart[b], s1 = bstart[b + 1];
    for (int e = s0 + t; e < s1; e += 256) {
        int v = ebuf[e];
        int dl = v >> 18;
        int p = atomicAdd(&pos[dl], 1);
        csr[base + loff[dl] + p] = v & 0x3FFFF;
    }
    __syncthreads();
    if (t < 128 && i < N_NODES) {
        int st = base + loff[t] + dv, en = base + loff[t] + pad;
        for (int q = st; q < en; ++q) csr[q] = N_NODES;  // pad -> zero row
    }
}

// ---------- layer1 fused with fc1: LDS-staged gather + broadcast MLP/transform ----------
__global__ __launch_bounds__(256) void k_layer1f(const float4* __restrict__ xd,
                                                 const int* __restrict__ row,
                                                 const int* __restrict__ csr,
                                                 const float* __restrict__ W,   // fc1_w [2][32]
                                                 const float* __restrict__ bf,  // fc1_b
                                                 const float* __restrict__ Wc,  // conv1_w
                                                 const float* __restrict__ bc,  // conv1_b
                                                 float* __restrict__ hout) {
    __shared__ float4 stage[8][16];
    __shared__ float arow[8][32];
    int g = threadIdx.x >> 5, l = threadIdx.x & 31, f = l;
    int t = blockIdx.x * 256 + threadIdx.x;
    int i = t >> 5;
    if (i >= N_NODES) return;
    float w0 = W[f], w1 = W[D + f], bb = bf[f];
    float wcol[D];
#pragma unroll
    for (int k = 0; k < D; ++k) wcol[k] = Wc[k * D + f];
    float4 sv = xd[i];
    float hs = fmaf(sv.x, w0, fmaf(sv.y, w1, bb));
    hs = hs > 0.f ? hs : 0.f;
    float a = hs * sv.z;  // self-loop
    int rs = row[i], re = row[i + 1];
    int j0 = rs;
    int cs = csr[j0 + (l & 15)];
    while (j0 < re) {
        int nxt = csr[j0 + 16 + (l & 15)];  // slack-safe prefetch
        if (l < 16) {
            int s2 = (j0 + l < re) ? cs : N_NODES;
            stage[g][l] = xd[s2];
        }
#pragma unroll
        for (int it = 0; it < 4; ++it) {
            if (j0 + it * 4 >= re) break;  // pad-4 rows
            float4 v0 = stage[g][it * 4 + 0];
            float4 v1 = stage[g][it * 4 + 1];
            float4 v2 = stage[g][it * 4 + 2];
            float4 v3 = stage[g][it * 4 + 3];
            float h0 = fmaf(v0.x, w0, fmaf(v0.y, w1, bb)); h0 = h0 > 0.f ? h0 : 0.f;
            float h1 = fmaf(v1.x, w0, fmaf(v1.y, w1, bb)); h1 = h1 > 0.f ? h1 : 0.f;
            float h2 = fmaf(v2.x, w0, fmaf(v2.y, w1, bb)); h2 = h2 > 0.f ? h2 : 0.f;
            float h3 = fmaf(v3.x, w0, fmaf(v3.y, w1, bb)); h3 = h3 > 0.f ? h3 : 0.f;
            a = fmaf(h0, v0.z, a);
            a = fmaf(h1, v1.z, a);
            a = fmaf(h2, v2.z, a);
            a = fmaf(h3, v3.z, a);
        }
        cs = nxt;
        j0 += 16;
    }
    float di = sv.z;
    a *= di;
    arow[g][f] = a;  // ds_write_b32, conflict-free
    float acc = 0.f;
#pragma unroll
    for (int q = 0; q < 8; ++q) {
        float4 aq = ((const float4*)arow[g])[q];  // broadcast read
        acc = fmaf(aq.x, wcol[4 * q + 0],
              fmaf(aq.y, wcol[4 * q + 1],
              fmaf(aq.z, wcol[4 * q + 2],
              fmaf(aq.w, wcol[4 * q + 3], acc))));
    }
    float v = acc + bc[f];
    v = v > 0.f ? v : 0.f;
    hout[t] = v * di;
}

// ---------- fused layer: 4-row float4 gather + VGPR-wcol transform ----------
__global__ __launch_bounds__(256) void k_layer(const float* __restrict__ hsc,
                                               const int* __restrict__ row,
                                               const int* __restrict__ csr,
                                               const float* __restrict__ dis,
                                               const float* __restrict__ W,
                                               const float* __restrict__ b,
                                               float* __restrict__ hout) {
    __shared__ float arow[8][32];
    int g = threadIdx.x >> 5, l = threadIdx.x & 31, f = l;
    int t = blockIdx.x * 256 + threadIdx.x;
    int i = t >> 5;
    if (i >= N_NODES) return;
    float wcol[D];
#pragma unroll
    for (int k = 0; k < D; ++k) wcol[k] = W[k * D + f];
    int c = l & 7;  // float4 chunk of the row
    const float4* rowf4 = (const float4*)hsc;
    float4 a4 = make_float4(0.f, 0.f, 0.f, 0.f);
    int rs = row[i], re = row[i + 1];
    int j0 = rs;
    int sidx = csr[j0 + (l & 15)];
    while (j0 < re) {
        int nxt = csr[j0 + 16 + (l & 15)];  // slack-safe prefetch
#pragma unroll
        for (int it = 0; it < 4; ++it) {
            if (j0 + it * 4 >= re) break;  // pad-4 rows
            int s = __shfl(sidx, it * 4 + (l >> 3), 32);
            float4 v = rowf4[s * 8 + c];  // 4 full rows (512B) per instruction
            a4.x += v.x; a4.y += v.y; a4.z += v.z; a4.w += v.w;
        }
        sidx = nxt;
        j0 += 16;
    }
    a4.x += __shfl_xor(a4.x, 8, 32);  a4.y += __shfl_xor(a4.y, 8, 32);
    a4.z += __shfl_xor(a4.z, 8, 32);  a4.w += __shfl_xor(a4.w, 8, 32);
    a4.x += __shfl_xor(a4.x, 16, 32); a4.y += __shfl_xor(a4.y, 16, 32);
    a4.z += __shfl_xor(a4.z, 16, 32); a4.w += __shfl_xor(a4.w, 16, 32);
    float4 sv = rowf4[i * 8 + c];  // self row
    a4.x += sv.x; a4.y += sv.y; a4.z += sv.z; a4.w += sv.w;
    float di = dis[i];
    a4.x *= di; a4.y *= di; a4.z *= di; a4.w *= di;
    if (l < 8) ((float4*)arow[g])[l] = a4;  // full aggregated row to LDS
    float acc = 0.f;
#pragma unroll
    for (int q = 0; q < 8; ++q) {
        float4 aq = ((const float4*)arow[g])[q];  // broadcast read
        acc = fmaf(aq.x, wcol[4 * q + 0],
              fmaf(aq.y, wcol[4 * q + 1],
              fmaf(aq.z, wcol[4 * q + 2],
              fmaf(aq.w, wcol[4 * q + 3], acc))));
    }
    float v = acc + b[f];
    v = v > 0.f ? v : 0.f;
    hout[t] = v * di;
}

// ---------- heads: same gather, two VGPR-wcol transforms + 32->1 dots ----------
__global__ __launch_bounds__(256) void k_heads(
    const float* __restrict__ hsc, const int* __restrict__ row,
    const int* __restrict__ csr, const float* __restrict__ dis,
    const float* __restrict__ W1, const float* __restrict__ b1,
    const float* __restrict__ W2, const float* __restrict__ b2,
    const float* __restrict__ fw1, const float* __restrict__ fb1,
    const float* __restrict__ fw2, const float* __restrict__ fb2,
    float* __restrict__ out) {
    __shared__ float arow[8][32];
    int g = threadIdx.x >> 5, l = threadIdx.x & 31, f = l;
    int t = blockIdx.x * 256 + threadIdx.x;
    int i = t >> 5;
    if (i >= N_NODES) return;
    float wc1[D], wc2[D];
#pragma unroll
    for (int k = 0; k < D; ++k) { wc1[k] = W1[k * D + f]; wc2[k] = W2[k * D + f]; }
    int c = l & 7;
    const float4* rowf4 = (const float4*)hsc;
    float4 a4 = make_float4(0.f, 0.f, 0.f, 0.f);
    int rs = row[i], re = row[i + 1];
    int j0 = rs;
    int sidx = csr[j0 + (l & 15)];
    while (j0 < re) {
        int nxt = csr[j0 + 16 + (l & 15)];
#pragma unroll
        for (int it = 0; it < 4; ++it) {
            if (j0 + it * 4 >= re) break;
            int s = __shfl(sidx, it * 4 + (l >> 3), 32);
            float4 v = rowf4[s * 8 + c];
            a4.x += v.x; a4.y += v.y; a4.z += v.z; a4.w += v.w;
        }
        sidx = nxt;
        j0 += 16;
    }
    a4.x += __shfl_xor(a4.x, 8, 32);  a4.y += __shfl_xor(a4.y, 8, 32);
    a4.z += __shfl_xor(a4.z, 8, 32);  a4.w += __shfl_xor(a4.w, 8, 32);
    a4.x += __shfl_xor(a4.x, 16, 32); a4.y += __shfl_xor(a4.y, 16, 32);
    a4.z += __shfl_xor(a4.z, 16, 32); a4.w += __shfl_xor(a4.w, 16, 32);
    float4 sv = rowf4[i * 8 + c];
    a4.x += sv.x; a4.y += sv.y; a4.z += sv.z; a4.w += sv.w;
    float di = dis[i];
    a4.x *= di; a4.y *= di; a4.z *= di; a4.w *= di;
    if (l < 8) ((float4*)arow[g])[l] = a4;
    float acc1 = 0.f, acc2 = 0.f;
#pragma unroll
    for (int q = 0; q < 8; ++q) {
        float4 aq = ((const float4*)arow[g])[q];
        acc1 = fmaf(aq.x, wc1[4 * q + 0],
               fmaf(aq.y, wc1[4 * q + 1],
               fmaf(aq.z, wc1[4 * q + 2],
               fmaf(aq.w, wc1[4 * q + 3], acc1))));
        acc2 = fmaf(aq.x, wc2[4 * q + 0],
               fmaf(aq.y, wc2[4 * q + 1],
               fmaf(aq.z, wc2[4 * q + 2],
               fmaf(aq.w, wc2[4 * q + 3], acc2))));
    }
    float v1 = acc1 + b1[f];
    v1 = (v1 > 0.f ? v1 : 0.f) * fw1[f];
    float v2 = acc2 + b2[f];
    v2 = (v2 > 0.f ? v2 : 0.f) * fw2[f];
#pragma unroll
    for (int o = 16; o > 0; o >>= 1) {
        v1 += __shfl_down(v1, o, 32);
        v2 += __shfl_down(v2, o, 32);
    }
    if (f == 0) {
        out[i * 2] = v1 + fb1[0];
        out[i * 2 + 1] = v2 + fb2[0];
    }
}

extern "C" void kernel_launch(void* const* d_in, const int* in_sizes, int n_in,
                              void* d_out, int out_size, void* d_ws, size_t ws_size,
                              hipStream_t stream) {
    const float* x       = (const float*)d_in[0];
    const int*   eidx    = (const int*)d_in[1];
    const float* fc1_w   = (const float*)d_in[2];
    const float* fc1_b   = (const float*)d_in[3];
    const float* conv1_w = (const float*)d_in[4];
    const float* conv1_b = (const float*)d_in[5];
    const float* conv2_w = (const float*)d_in[6];
    const float* conv2_b = (const float*)d_in[7];
    const float* c31_w   = (const float*)d_in[8];
    const float* c31_b   = (const float*)d_in[9];
    const float* c32_w   = (const float*)d_in[10];
    const float* c32_b   = (const float*)d_in[11];
    const float* fc21_w  = (const float*)d_in[12];
    const float* fc21_b  = (const float*)d_in[13];
    const float* fc22_w  = (const float*)d_in[14];
    const float* fc22_b  = (const float*)d_in[15];
    float* out = (float*)d_out;

    const int* src = eidx;            // edge_index[0]
    const int* dst = eidx + N_EDGES;  // edge_index[1]

    // ----- workspace layout (int units; 16B alignment preserved) -----
    int*   wsb    = (int*)d_ws;
    int*   csr    = wsb;                        // CSR_CAP
    int*   irow   = wsb + 2850064;              // 150,004
    int*   bstart = wsb + 3000068;              // 1,174
    int*   pbase  = wsb + 3001242;              // 1,174
    float* dis    = (float*)(wsb + 3002416);    // 150,000
    float* HA     = (float*)(wsb + 3152416);    // 4,800,032 floats
    float* HB     = (float*)(wsb + 7952448);    // 4,800,032 floats
    // transient aliases inside HA (dead before k_layer writes HA):
    int*    cnt  = (int*)HA;                    // 686,792
    int*    ebuf = (int*)HA + 700000;           // 2,400,000
    float4* xd   = (float4*)((int*)HA + 3100016);  // (N+1) float4
    // deg aliases HB low (dead before k_layer1f writes HB):
    int*    deg  = (int*)HB;                    // 150,000

    const int BLK = 256;
    const int gL  = (N_NODES * D + BLK - 1) / BLK;  // 18750

    // ----- CSR build (no global atomics) -----
    k_zero_row<<<1, 32, 0, stream>>>(HA, HB);
    kA_hist<<<NCHK, BLK, 0, stream>>>(dst, cnt);
    kS1<<<(NBUCK + 31) / 32, BLK, 0, stream>>>(cnt, bstart);
    k_scan_small<<<1, BLK, 0, stream>>>(bstart, NBUCK);
    kB_scatter<<<NCHK, BLK, 0, stream>>>(src, dst, cnt, bstart, ebuf);
    kC1<<<NBUCK, BLK, 0, stream>>>(ebuf, bstart, (const float2*)x, deg, dis, xd, pbase);
    k_scan_small<<<1, BLK, 0, stream>>>(pbase, NBUCK);
    kC3<<<NBUCK, BLK, 0, stream>>>(ebuf, bstart, deg, pbase, csr, irow);

    // ----- network -----
    k_layer1f<<<gL, BLK, 0, stream>>>(xd, irow, csr, fc1_w, fc1_b, conv1_w, conv1_b, HB);
    k_layer<<<gL, BLK, 0, stream>>>(HB, irow, csr, dis, conv2_w, conv2_b, HA);
    k_heads<<<gL, BLK, 0, stream>>>(HA, irow, csr, dis, c31_w, c31_b, c32_w, c32_b,
                                    fc21_w, fc21_b, fc22_w, fc22_b, out);
}

// Round 9
// 257.604 us; speedup vs baseline: 5.8800x; 1.1746x over previous
//
#include <hip/hip_runtime.h>

#define N_NODES 150000
#define N_EDGES 2400000
#define D 32
#define NBUCK 1172                 // ceil(N/128)
#define CHUNK 4096
#define NCHK 586                   // ceil(E/CHUNK)
#define CSR_CAP (N_EDGES + 3 * N_NODES + 64)

// ---------- pass A: per-chunk LDS histogram of buckets ----------
__global__ __launch_bounds__(256) void kA_hist(const int* __restrict__ dst,
                                               int* __restrict__ cnt) {
    __shared__ int bins[NBUCK];
    int t = threadIdx.x;
    for (int k = t; k < NBUCK; k += 256) bins[k] = 0;
    __syncthreads();
    int e0 = blockIdx.x * CHUNK;
#pragma unroll
    for (int r = 0; r < CHUNK / 256; ++r) {
        int e = e0 + r * 256 + t;
        if (e < N_EDGES) atomicAdd(&bins[dst[e] >> 7], 1);
    }
    __syncthreads();
    for (int k = t; k < NBUCK; k += 256) cnt[blockIdx.x * NBUCK + k] = bins[k];
}

// ---------- S1: per-bucket exclusive scan over chunks ----------
__global__ __launch_bounds__(256) void kS1(int* __restrict__ cnt, int* __restrict__ bstart) {
    __shared__ int tile[8][33];
    __shared__ int carry[32];
    int t = threadIdx.x;
    int tl = t & 31, tr = t >> 5;
    int b = blockIdx.x * 32 + tl;
    if (t < 32) carry[t] = 0;
    __syncthreads();
    for (int c0 = 0; c0 < NCHK; c0 += 8) {
        int c = c0 + tr;
        int v = (c < NCHK && b < NBUCK) ? cnt[c * NBUCK + b] : 0;
        tile[tr][tl] = v;
        __syncthreads();
        if (t < 32) {
            int s = carry[t];
#pragma unroll
            for (int r = 0; r < 8; ++r) { int x = tile[r][t]; tile[r][t] = s; s += x; }
            carry[t] = s;
        }
        __syncthreads();
        if (c < NCHK && b < NBUCK) cnt[c * NBUCK + b] = tile[tr][tl];
        __syncthreads();
    }
    if (t < 32 && b < NBUCK) bstart[b] = carry[t];
}

// ---------- single-block exclusive scan in place; a[m] = total ----------
__global__ void k_scan_small(int* __restrict__ a, int m) {
    __shared__ int s[256];
    __shared__ int carry;
    int t = threadIdx.x;
    if (t == 0) carry = 0;
    __syncthreads();
    for (int base = 0; base < m; base += 256) {
        int v = (base + t < m) ? a[base + t] : 0;
        s[t] = v;
        __syncthreads();
        for (int off = 1; off < 256; off <<= 1) {
            int add = (t >= off) ? s[t - off] : 0;
            __syncthreads();
            s[t] += add;
            __syncthreads();
        }
        int c0 = carry;
        if (base + t < m) a[base + t] = c0 + s[t] - v;
        int bsum = s[255];
        __syncthreads();
        if (t == 0) carry = c0 + bsum;
        __syncthreads();
    }
    if (t == 0) a[m] = carry;
}

// ---------- pass B: scatter packed edges into bucket-grouped ebuf ----------
__global__ __launch_bounds__(256) void kB_scatter(const int* __restrict__ src,
                                                  const int* __restrict__ dst,
                                                  const int* __restrict__ cnt,
                                                  const int* __restrict__ bstart,
                                                  int* __restrict__ ebuf) {
    __shared__ int lofs[NBUCK];
    int t = threadIdx.x;
    for (int k = t; k < NBUCK; k += 256)
        lofs[k] = bstart[k] + cnt[blockIdx.x * NBUCK + k];
    __syncthreads();
    int e0 = blockIdx.x * CHUNK;
#pragma unroll
    for (int r = 0; r < CHUNK / 256; ++r) {
        int e = e0 + r * 256 + t;
        if (e < N_EDGES) {
            int d = dst[e];
            int p = atomicAdd(&lofs[d >> 7], 1);
            ebuf[p] = src[e] | ((d & 127) << 18);  // src < 2^18
        }
    }
}

// ---------- C1: per-bucket degree histogram -> deg, dis, xd, padded totals ----------
__global__ __launch_bounds__(256) void kC1(const int* __restrict__ ebuf,
                                           const int* __restrict__ bstart,
                                           const float2* __restrict__ x,
                                           int* __restrict__ deg,
                                           float* __restrict__ dis,
                                           float4* __restrict__ xd,
                                           int* __restrict__ pbase) {
    __shared__ int hist[128];
    __shared__ int sc[128];
    int b = blockIdx.x, t = threadIdx.x;
    if (t < 128) hist[t] = 0;
    __syncthreads();
    int s0 = bstart[b], s1 = bstart[b + 1];
    for (int e = s0 + t; e < s1; e += 256) atomicAdd(&hist[ebuf[e] >> 18], 1);
    __syncthreads();
    int i = b * 128 + t;
    if (t < 128) {
        int dv = hist[t];
        if (i < N_NODES) {
            deg[i] = dv;
            float dz = rsqrtf((float)dv + 1.0f);
            dis[i] = dz;
            float2 xv = x[i];
            xd[i] = make_float4(xv.x, xv.y, dz, 0.f);
        } else if (i == N_NODES) {
            xd[i] = make_float4(0.f, 0.f, 0.f, 0.f);
        }
        sc[t] = (i < N_NODES) ? ((dv + 3) & ~3) : 0;  // pad-4
    }
    __syncthreads();
    for (int s = 64; s > 0; s >>= 1) {
        if (t < s) sc[t] += sc[t + s];
        __syncthreads();
    }
    if (t == 0) pbase[b] = sc[0];
}

// ---------- C3: per-bucket CSR fill (pad-4 rows) + irow + slack + zero rows ----------
__global__ __launch_bounds__(256) void kC3(const int* __restrict__ ebuf,
                                           const int* __restrict__ bstart,
                                           const int* __restrict__ deg,
                                           const int* __restrict__ pbase,
                                           int* __restrict__ csr,
                                           int* __restrict__ irow,
                                           float* __restrict__ HA,
                                           float* __restrict__ HB) {
    __shared__ int sc[128];
    __shared__ int loff[128];
    __shared__ int pos[128];
    int b = blockIdx.x, t = threadIdx.x;
    if (b == 0) {
        if (t == 0) irow[N_NODES] = pbase[NBUCK];
        if (t < 64) csr[pbase[NBUCK] + t] = N_NODES;  // slack for 16-wide reads + prefetch
        if (t >= 64 && t < 96) HA[(size_t)N_NODES * D + (t - 64)] = 0.f;   // zero row
        if (t >= 96 && t < 128) HB[(size_t)N_NODES * D + (t - 96)] = 0.f;  // zero row
    }
    int i = b * 128 + t;
    int dv = 0, pad = 0;
    if (t < 128) {
        dv = (i < N_NODES) ? deg[i] : 0;
        pad = (dv + 3) & ~3;
        sc[t] = pad;
        pos[t] = 0;
    }
    __syncthreads();
    for (int off = 1; off < 128; off <<= 1) {
        int add = 0;
        if (t < 128 && t >= off) add = sc[t - off];
        __syncthreads();
        if (t < 128) sc[t] += add;
        __syncthreads();
    }
    int base = pbase[b];
    if (t < 128) {
        loff[t] = sc[t] - pad;  // exclusive prefix
        if (i < N_NODES) irow[i] = base + loff[t];
    }
    __syncthreads();
    int s0 = bstart[b], s1 = bstart[b + 1];
    for (int e = s0 + t; e < s1; e += 256) {
        int v = ebuf[e];
        int dl = v >> 18;
        int p = atomicAdd(&pos[dl], 1);
        csr[base + loff[dl] + p] = v & 0x3FFFF;
    }
    __syncthreads();
    if (t < 128 && i < N_NODES) {
        int st = base + loff[t] + dv, en = base + loff[t] + pad;
        for (int q = st; q < en; ++q) csr[q] = N_NODES;  // pad -> zero row
    }
}

// ---------- layer1 fused with fc1: LDS-staged gather + broadcast MLP/transform ----------
__global__ __launch_bounds__(256) void k_layer1f(const float4* __restrict__ xd,
                                                 const int* __restrict__ row,
                                                 const int* __restrict__ csr,
                                                 const float* __restrict__ W,   // fc1_w [2][32]
                                                 const float* __restrict__ bf,  // fc1_b
                                                 const float* __restrict__ Wc,  // conv1_w
                                                 const float* __restrict__ bc,  // conv1_b
                                                 float* __restrict__ hout) {
    __shared__ float4 stage[8][16];
    __shared__ float arow[8][32];
    int g = threadIdx.x >> 5, l = threadIdx.x & 31, f = l;
    int t = blockIdx.x * 256 + threadIdx.x;
    int i = t >> 5;
    if (i >= N_NODES) return;
    float w0 = W[f], w1 = W[D + f], bb = bf[f];
    float wcol[D];
#pragma unroll
    for (int k = 0; k < D; ++k) wcol[k] = Wc[k * D + f];
    float4 sv = xd[i];
    float hs = fmaf(sv.x, w0, fmaf(sv.y, w1, bb));
    hs = hs > 0.f ? hs : 0.f;
    float a = hs * sv.z;  // self-loop
    int rs = row[i], re = row[i + 1];
    int j0 = rs;
    int cs = csr[j0 + (l & 15)];
    while (j0 < re) {
        int nxt = csr[j0 + 16 + (l & 15)];  // slack-safe prefetch
        if (l < 16) {
            int s2 = (j0 + l < re) ? cs : N_NODES;
            stage[g][l] = xd[s2];
        }
#pragma unroll
        for (int it = 0; it < 4; ++it) {
            if (j0 + it * 4 >= re) break;  // pad-4 rows
            float4 v0 = stage[g][it * 4 + 0];
            float4 v1 = stage[g][it * 4 + 1];
            float4 v2 = stage[g][it * 4 + 2];
            float4 v3 = stage[g][it * 4 + 3];
            float h0 = fmaf(v0.x, w0, fmaf(v0.y, w1, bb)); h0 = h0 > 0.f ? h0 : 0.f;
            float h1 = fmaf(v1.x, w0, fmaf(v1.y, w1, bb)); h1 = h1 > 0.f ? h1 : 0.f;
            float h2 = fmaf(v2.x, w0, fmaf(v2.y, w1, bb)); h2 = h2 > 0.f ? h2 : 0.f;
            float h3 = fmaf(v3.x, w0, fmaf(v3.y, w1, bb)); h3 = h3 > 0.f ? h3 : 0.f;
            a = fmaf(h0, v0.z, a);
            a = fmaf(h1, v1.z, a);
            a = fmaf(h2, v2.z, a);
            a = fmaf(h3, v3.z, a);
        }
        cs = nxt;
        j0 += 16;
    }
    float di = sv.z;
    a *= di;
    arow[g][f] = a;
    float acc = 0.f;
#pragma unroll
    for (int q = 0; q < 8; ++q) {
        float4 aq = ((const float4*)arow[g])[q];  // broadcast read
        acc = fmaf(aq.x, wcol[4 * q + 0],
              fmaf(aq.y, wcol[4 * q + 1],
              fmaf(aq.z, wcol[4 * q + 2],
              fmaf(aq.w, wcol[4 * q + 3], acc))));
    }
    float v = acc + bc[f];
    v = v > 0.f ? v : 0.f;
    hout[t] = v * di;
}

// ---------- fused layer: 2-node batched gather (8 loads in flight) + transform ----------
__global__ __launch_bounds__(256) void k_layer(const float* __restrict__ hsc,
                                               const int* __restrict__ row,
                                               const int* __restrict__ csr,
                                               const float* __restrict__ dis,
                                               const float* __restrict__ W,
                                               const float* __restrict__ b,
                                               float* __restrict__ hout) {
    __shared__ float arow[16][32];
    int g = threadIdx.x >> 5, l = threadIdx.x & 31, f = l;
    int gg = blockIdx.x * 8 + g;
    int iA = gg * 2, iB = iA + 1;  // N even; exact grid
    float wcol[D];
#pragma unroll
    for (int k = 0; k < D; ++k) wcol[k] = W[k * D + f];
    int c = l & 7, l16 = l & 15, sub = l >> 3;
    const float4* rowf4 = (const float4*)hsc;
    int rsA = row[iA], mid = row[iB], reB = row[iB + 1];
    float4 aA = make_float4(0.f, 0.f, 0.f, 0.f);
    float4 aB = make_float4(0.f, 0.f, 0.f, 0.f);
    int jA = rsA, jB = mid;
    int csA = csr[jA + l16], csB = csr[jB + l16];
    while (jA < mid && jB < reB) {
        int nA = csr[jA + 16 + l16], nB = csr[jB + 16 + l16];
        float4 vA[4], vB[4];
#pragma unroll
        for (int it = 0; it < 4; ++it)
            if (jA + it * 4 < mid) { int s = __shfl(csA, it * 4 + sub, 32); vA[it] = rowf4[s * 8 + c]; }
#pragma unroll
        for (int it = 0; it < 4; ++it)
            if (jB + it * 4 < reB) { int s = __shfl(csB, it * 4 + sub, 32); vB[it] = rowf4[s * 8 + c]; }
#pragma unroll
        for (int it = 0; it < 4; ++it) {
            if (jA + it * 4 < mid) { aA.x += vA[it].x; aA.y += vA[it].y; aA.z += vA[it].z; aA.w += vA[it].w; }
            if (jB + it * 4 < reB) { aB.x += vB[it].x; aB.y += vB[it].y; aB.z += vB[it].z; aB.w += vB[it].w; }
        }
        csA = nA; csB = nB; jA += 16; jB += 16;
    }
    while (jA < mid) {
        int nA = csr[jA + 16 + l16];
        float4 vA[4];
#pragma unroll
        for (int it = 0; it < 4; ++it)
            if (jA + it * 4 < mid) { int s = __shfl(csA, it * 4 + sub, 32); vA[it] = rowf4[s * 8 + c]; }
#pragma unroll
        for (int it = 0; it < 4; ++it)
            if (jA + it * 4 < mid) { aA.x += vA[it].x; aA.y += vA[it].y; aA.z += vA[it].z; aA.w += vA[it].w; }
        csA = nA; jA += 16;
    }
    while (jB < reB) {
        int nB = csr[jB + 16 + l16];
        float4 vB[4];
#pragma unroll
        for (int it = 0; it < 4; ++it)
            if (jB + it * 4 < reB) { int s = __shfl(csB, it * 4 + sub, 32); vB[it] = rowf4[s * 8 + c]; }
#pragma unroll
        for (int it = 0; it < 4; ++it)
            if (jB + it * 4 < reB) { aB.x += vB[it].x; aB.y += vB[it].y; aB.z += vB[it].z; aB.w += vB[it].w; }
        csB = nB; jB += 16;
    }
    aA.x += __shfl_xor(aA.x, 8, 32);  aA.y += __shfl_xor(aA.y, 8, 32);
    aA.z += __shfl_xor(aA.z, 8, 32);  aA.w += __shfl_xor(aA.w, 8, 32);
    aA.x += __shfl_xor(aA.x, 16, 32); aA.y += __shfl_xor(aA.y, 16, 32);
    aA.z += __shfl_xor(aA.z, 16, 32); aA.w += __shfl_xor(aA.w, 16, 32);
    aB.x += __shfl_xor(aB.x, 8, 32);  aB.y += __shfl_xor(aB.y, 8, 32);
    aB.z += __shfl_xor(aB.z, 8, 32);  aB.w += __shfl_xor(aB.w, 8, 32);
    aB.x += __shfl_xor(aB.x, 16, 32); aB.y += __shfl_xor(aB.y, 16, 32);
    aB.z += __shfl_xor(aB.z, 16, 32); aB.w += __shfl_xor(aB.w, 16, 32);
    float4 svA = rowf4[iA * 8 + c], svB = rowf4[iB * 8 + c];
    float diA = dis[iA], diB = dis[iB];
    aA.x = (aA.x + svA.x) * diA; aA.y = (aA.y + svA.y) * diA;
    aA.z = (aA.z + svA.z) * diA; aA.w = (aA.w + svA.w) * diA;
    aB.x = (aB.x + svB.x) * diB; aB.y = (aB.y + svB.y) * diB;
    aB.z = (aB.z + svB.z) * diB; aB.w = (aB.w + svB.w) * diB;
    if (l < 8) ((float4*)arow[g * 2])[l] = aA;
    else if (l < 16) ((float4*)arow[g * 2 + 1])[l - 8] = aB;
    float accA = 0.f, accB = 0.f;
#pragma unroll
    for (int q = 0; q < 8; ++q) {
        float4 qa = ((const float4*)arow[g * 2])[q];
        float4 qb = ((const float4*)arow[g * 2 + 1])[q];
        accA = fmaf(qa.x, wcol[4 * q + 0],
               fmaf(qa.y, wcol[4 * q + 1],
               fmaf(qa.z, wcol[4 * q + 2],
               fmaf(qa.w, wcol[4 * q + 3], accA))));
        accB = fmaf(qb.x, wcol[4 * q + 0],
               fmaf(qb.y, wcol[4 * q + 1],
               fmaf(qb.z, wcol[4 * q + 2],
               fmaf(qb.w, wcol[4 * q + 3], accB))));
    }
    float vA_ = accA + b[f]; vA_ = vA_ > 0.f ? vA_ : 0.f;
    float vB_ = accB + b[f]; vB_ = vB_ > 0.f ? vB_ : 0.f;
    hout[iA * D + f] = vA_ * diA;
    hout[iB * D + f] = vB_ * diB;
}

// ---------- heads: 2-node batched gather, two transforms + 32->1 dots ----------
__global__ __launch_bounds__(256) void k_heads(
    const float* __restrict__ hsc, const int* __restrict__ row,
    const int* __restrict__ csr, const float* __restrict__ dis,
    const float* __restrict__ W1, const float* __restrict__ b1,
    const float* __restrict__ W2, const float* __restrict__ b2,
    const float* __restrict__ fw1, const float* __restrict__ fb1,
    const float* __restrict__ fw2, const float* __restrict__ fb2,
    float* __restrict__ out) {
    __shared__ float arow[16][32];
    int g = threadIdx.x >> 5, l = threadIdx.x & 31, f = l;
    int gg = blockIdx.x * 8 + g;
    int iA = gg * 2, iB = iA + 1;
    float wc1[D], wc2[D];
#pragma unroll
    for (int k = 0; k < D; ++k) { wc1[k] = W1[k * D + f]; wc2[k] = W2[k * D + f]; }
    int c = l & 7, l16 = l & 15, sub = l >> 3;
    const float4* rowf4 = (const float4*)hsc;
    int rsA = row[iA], mid = row[iB], reB = row[iB + 1];
    float4 aA = make_float4(0.f, 0.f, 0.f, 0.f);
    float4 aB = make_float4(0.f, 0.f, 0.f, 0.f);
    int jA = rsA, jB = mid;
    int csA = csr[jA + l16], csB = csr[jB + l16];
    while (jA < mid && jB < reB) {
        int nA = csr[jA + 16 + l16], nB = csr[jB + 16 + l16];
        float4 vA[4], vB[4];
#pragma unroll
        for (int it = 0; it < 4; ++it)
            if (jA + it * 4 < mid) { int s = __shfl(csA, it * 4 + sub, 32); vA[it] = rowf4[s * 8 + c]; }
#pragma unroll
        for (int it = 0; it < 4; ++it)
            if (jB + it * 4 < reB) { int s = __shfl(csB, it * 4 + sub, 32); vB[it] = rowf4[s * 8 + c]; }
#pragma unroll
        for (int it = 0; it < 4; ++it) {
            if (jA + it * 4 < mid) { aA.x += vA[it].x; aA.y += vA[it].y; aA.z += vA[it].z; aA.w += vA[it].w; }
            if (jB + it * 4 < reB) { aB.x += vB[it].x; aB.y += vB[it].y; aB.z += vB[it].z; aB.w += vB[it].w; }
        }
        csA = nA; csB = nB; jA += 16; jB += 16;
    }
    while (jA < mid) {
        int nA = csr[jA + 16 + l16];
        float4 vA[4];
#pragma unroll
        for (int it = 0; it < 4; ++it)
            if (jA + it * 4 < mid) { int s = __shfl(csA, it * 4 + sub, 32); vA[it] = rowf4[s * 8 + c]; }
#pragma unroll
        for (int it = 0; it < 4; ++it)
            if (jA + it * 4 < mid) { aA.x += vA[it].x; aA.y += vA[it].y; aA.z += vA[it].z; aA.w += vA[it].w; }
        csA = nA; jA += 16;
    }
    while (jB < reB) {
        int nB = csr[jB + 16 + l16];
        float4 vB[4];
#pragma unroll
        for (int it = 0; it < 4; ++it)
            if (jB + it * 4 < reB) { int s = __shfl(csB, it * 4 + sub, 32); vB[it] = rowf4[s * 8 + c]; }
#pragma unroll
        for (int it = 0; it < 4; ++it)
            if (jB + it * 4 < reB) { aB.x += vB[it].x; aB.y += vB[it].y; aB.z += vB[it].z; aB.w += vB[it].w; }
        csB = nB; jB += 16;
    }
    aA.x += __shfl_xor(aA.x, 8, 32);  aA.y += __shfl_xor(aA.y, 8, 32);
    aA.z += __shfl_xor(aA.z, 8, 32);  aA.w += __shfl_xor(aA.w, 8, 32);
    aA.x += __shfl_xor(aA.x, 16, 32); aA.y += __shfl_xor(aA.y, 16, 32);
    aA.z += __shfl_xor(aA.z, 16, 32); aA.w += __shfl_xor(aA.w, 16, 32);
    aB.x += __shfl_xor(aB.x, 8, 32);  aB.y += __shfl_xor(aB.y, 8, 32);
    aB.z += __shfl_xor(aB.z, 8, 32);  aB.w += __shfl_xor(aB.w, 8, 32);
    aB.x += __shfl_xor(aB.x, 16, 32); aB.y += __shfl_xor(aB.y, 16, 32);
    aB.z += __shfl_xor(aB.z, 16, 32); aB.w += __shfl_xor(aB.w, 16, 32);
    float4 svA = rowf4[iA * 8 + c], svB = rowf4[iB * 8 + c];
    float diA = dis[iA], diB = dis[iB];
    aA.x = (aA.x + svA.x) * diA; aA.y = (aA.y + svA.y) * diA;
    aA.z = (aA.z + svA.z) * diA; aA.w = (aA.w + svA.w) * diA;
    aB.x = (aB.x + svB.x) * diB; aB.y = (aB.y + svB.y) * diB;
    aB.z = (aB.z + svB.z) * diB; aB.w = (aB.w + svB.w) * diB;
    if (l < 8) ((float4*)arow[g * 2])[l] = aA;
    else if (l < 16) ((float4*)arow[g * 2 + 1])[l - 8] = aB;
    float a1A = 0.f, a2A = 0.f, a1B = 0.f, a2B = 0.f;
#pragma unroll
    for (int q = 0; q < 8; ++q) {
        float4 qa = ((const float4*)arow[g * 2])[q];
        float4 qb = ((const float4*)arow[g * 2 + 1])[q];
        a1A = fmaf(qa.x, wc1[4 * q + 0], fmaf(qa.y, wc1[4 * q + 1],
              fmaf(qa.z, wc1[4 * q + 2], fmaf(qa.w, wc1[4 * q + 3], a1A))));
        a2A = fmaf(qa.x, wc2[4 * q + 0], fmaf(qa.y, wc2[4 * q + 1],
              fmaf(qa.z, wc2[4 * q + 2], fmaf(qa.w, wc2[4 * q + 3], a2A))));
        a1B = fmaf(qb.x, wc1[4 * q + 0], fmaf(qb.y, wc1[4 * q + 1],
              fmaf(qb.z, wc1[4 * q + 2], fmaf(qb.w, wc1[4 * q + 3], a1B))));
        a2B = fmaf(qb.x, wc2[4 * q + 0], fmaf(qb.y, wc2[4 * q + 1],
              fmaf(qb.z, wc2[4 * q + 2], fmaf(qb.w, wc2[4 * q + 3], a2B))));
    }
    float v1A = a1A + b1[f]; v1A = (v1A > 0.f ? v1A : 0.f) * fw1[f];
    float v2A = a2A + b2[f]; v2A = (v2A > 0.f ? v2A : 0.f) * fw2[f];
    float v1B = a1B + b1[f]; v1B = (v1B > 0.f ? v1B : 0.f) * fw1[f];
    float v2B = a2B + b2[f]; v2B = (v2B > 0.f ? v2B : 0.f) * fw2[f];
#pragma unroll
    for (int o = 16; o > 0; o >>= 1) {
        v1A += __shfl_down(v1A, o, 32);
        v2A += __shfl_down(v2A, o, 32);
        v1B += __shfl_down(v1B, o, 32);
        v2B += __shfl_down(v2B, o, 32);
    }
    if (l == 0) {
        float4 o4 = make_float4(v1A + fb1[0], v2A + fb2[0], v1B + fb1[0], v2B + fb2[0]);
        *(float4*)&out[iA * 2] = o4;  // iA even -> 16B aligned
    }
}

extern "C" void kernel_launch(void* const* d_in, const int* in_sizes, int n_in,
                              void* d_out, int out_size, void* d_ws, size_t ws_size,
                              hipStream_t stream) {
    const float* x       = (const float*)d_in[0];
    const int*   eidx    = (const int*)d_in[1];
    const float* fc1_w   = (const float*)d_in[2];
    const float* fc1_b   = (const float*)d_in[3];
    const float* conv1_w = (const float*)d_in[4];
    const float* conv1_b = (const float*)d_in[5];
    const float* conv2_w = (const float*)d_in[6];
    const float* conv2_b = (const float*)d_in[7];
    const float* c31_w   = (const float*)d_in[8];
    const float* c31_b   = (const float*)d_in[9];
    const float* c32_w   = (const float*)d_in[10];
    const float* c32_b   = (const float*)d_in[11];
    const float* fc21_w  = (const float*)d_in[12];
    const float* fc21_b  = (const float*)d_in[13];
    const float* fc22_w  = (const float*)d_in[14];
    const float* fc22_b  = (const float*)d_in[15];
    float* out = (float*)d_out;

    const int* src = eidx;            // edge_index[0]
    const int* dst = eidx + N_EDGES;  // edge_index[1]

    // ----- workspace layout (int units; 16B alignment preserved) -----
    int*   wsb    = (int*)d_ws;
    int*   csr    = wsb;                        // CSR_CAP
    int*   irow   = wsb + 2850064;              // 150,004
    int*   bstart = wsb + 3000068;              // 1,174
    int*   pbase  = wsb + 3001242;              // 1,174
    float* dis    = (float*)(wsb + 3002416);    // 150,000
    float* HA     = (float*)(wsb + 3152416);    // 4,800,032 floats
    float* HB     = (float*)(wsb + 7952448);    // 4,800,032 floats
    // transient aliases inside HA (dead before k_layer writes HA):
    int*    cnt  = (int*)HA;                    // 686,792
    int*    ebuf = (int*)HA + 700000;           // 2,400,000
    float4* xd   = (float4*)((int*)HA + 3100016);  // (N+1) float4
    // deg aliases HB low (dead before k_layer1f writes HB):
    int*    deg  = (int*)HB;                    // 150,000

    const int BLK = 256;
    const int gL  = (N_NODES * D + BLK - 1) / BLK;  // 18750 (layer1f)
    const int gL2 = N_NODES / 16;                    // 9375 (2-node batched kernels)

    // ----- CSR build (no global atomics) -----
    kA_hist<<<NCHK, BLK, 0, stream>>>(dst, cnt);
    kS1<<<(NBUCK + 31) / 32, BLK, 0, stream>>>(cnt, bstart);
    k_scan_small<<<1, BLK, 0, stream>>>(bstart, NBUCK);
    kB_scatter<<<NCHK, BLK, 0, stream>>>(src, dst, cnt, bstart, ebuf);
    kC1<<<NBUCK, BLK, 0, stream>>>(ebuf, bstart, (const float2*)x, deg, dis, xd, pbase);
    k_scan_small<<<1, BLK, 0, stream>>>(pbase, NBUCK);
    kC3<<<NBUCK, BLK, 0, stream>>>(ebuf, bstart, deg, pbase, csr, irow, HA, HB);

    // ----- network -----
    k_layer1f<<<gL, BLK, 0, stream>>>(xd, irow, csr, fc1_w, fc1_b, conv1_w, conv1_b, HB);
    k_layer<<<gL2, BLK, 0, stream>>>(HB, irow, csr, dis, conv2_w, conv2_b, HA);
    k_heads<<<gL2, BLK, 0, stream>>>(HA, irow, csr, dis, c31_w, c31_b, c32_w, c32_b,
                                     fc21_w, fc21_b, fc22_w, fc22_b, out);
}